// Round 1
// baseline (2421.286 us; speedup 1.0000x reference)
//
#include <hip/hip_runtime.h>
#include <math.h>

// MultiomicTransformer on MI355X — Round 1: correct fp32 baseline.
// B=8 W=2048 WIN=1024 D=512 NH=8 HD=64 DFF=2048 L=4 KS=4 G=2048 S=512

namespace {
constexpr int kB    = 8;
constexpr int kWIN  = 1024;
constexpr int kD    = 512;
constexpr int kNH   = 8;
constexpr int kDFF  = 2048;
constexpr int kL    = 4;
constexpr int kS    = 512;           // W / KS
constexpr int kG    = 2048;
constexpr int kNTOK = kB * kS;       // 4096
}

// ---------------------------------------------------------------- pool (mean over 4 rows, fused before win-proj: pooling commutes with linear map)
__global__ __launch_bounds__(256) void pool_windows_k(const float* __restrict__ win,
                                                      float* __restrict__ pw)
{
    int idx = blockIdx.x * 256 + threadIdx.x;     // float4 id over 4096*256
    int n   = idx >> 8;                           // token row 0..4095
    int c4  = (idx & 255) << 2;                   // col 0..1023 step 4
    int b = n >> 9, s = n & 511;
    const float* base = win + ((size_t)(b * 2048 + s * 4)) * 1024 + c4;
    float4 a = *(const float4*)(base);
    float4 b2 = *(const float4*)(base + 1024);
    float4 c = *(const float4*)(base + 2048);
    float4 d = *(const float4*)(base + 3072);
    float4 r;
    r.x = (a.x + b2.x + c.x + d.x) * 0.25f;
    r.y = (a.y + b2.y + c.y + d.y) * 0.25f;
    r.z = (a.z + b2.z + c.z + d.z) * 0.25f;
    r.w = (a.w + b2.w + c.w + d.w) * 0.25f;
    *(float4*)&pw[(size_t)n * 1024 + c4] = r;
}

// ---------------------------------------------------------------- generic fp32 GEMM: C[M,N] = A[M,K] * Bw[N,K]^T (+bias)(+posenc)(+res)(+relu)
// 64x64x32 tile, 256 threads, 4x4 micro-tile. LDS k-major with +4 pad.
template<bool BIAS, bool RES, bool RELU, bool POSENC>
__global__ __launch_bounds__(256) void gemm64_k(
    const float* __restrict__ A, const float* __restrict__ Bw,
    const float* __restrict__ bias, const float* __restrict__ Res,
    float* __restrict__ C, int M, int N, int K)
{
    __shared__ float As[32][68];
    __shared__ float Bs[32][68];
    const int n0 = blockIdx.x * 64, m0 = blockIdx.y * 64;
    const int tid = threadIdx.x, tx = tid & 15, ty = tid >> 4;
    float acc[4][4] = {};
    for (int k0 = 0; k0 < K; k0 += 32) {
        #pragma unroll
        for (int e = 0; e < 2; ++e) {
            int f = tid + e * 256;                // 512 float4s per operand tile
            int r = f >> 3, c4 = (f & 7) << 2;
            float4 a = *(const float4*)&A[(size_t)(m0 + r) * K + k0 + c4];
            As[c4 + 0][r] = a.x; As[c4 + 1][r] = a.y; As[c4 + 2][r] = a.z; As[c4 + 3][r] = a.w;
            float4 bb = *(const float4*)&Bw[(size_t)(n0 + r) * K + k0 + c4];
            Bs[c4 + 0][r] = bb.x; Bs[c4 + 1][r] = bb.y; Bs[c4 + 2][r] = bb.z; Bs[c4 + 3][r] = bb.w;
        }
        __syncthreads();
        #pragma unroll
        for (int kk = 0; kk < 32; ++kk) {
            float av[4], bv[4];
            float4 t = *(const float4*)&As[kk][ty * 4];
            av[0] = t.x; av[1] = t.y; av[2] = t.z; av[3] = t.w;
            float4 u = *(const float4*)&Bs[kk][tx * 4];
            bv[0] = u.x; bv[1] = u.y; bv[2] = u.z; bv[3] = u.w;
            #pragma unroll
            for (int i = 0; i < 4; ++i)
                #pragma unroll
                for (int j = 0; j < 4; ++j)
                    acc[i][j] += av[i] * bv[j];
        }
        __syncthreads();
    }
    #pragma unroll
    for (int i = 0; i < 4; ++i) {
        int m = m0 + ty * 4 + i;
        float4 outv;
        float* op = (float*)&outv;
        #pragma unroll
        for (int j = 0; j < 4; ++j) {
            int n = n0 + tx * 4 + j;
            float v = acc[i][j];
            if (BIAS) v += bias[n];
            if (POSENC) {
                int s = m & 511;                  // token index within sequence (S=512)
                float fr = expf((float)(n & ~1) * -0.01798894604f);  // exp(-2i*ln(1e4)/512)
                v += (n & 1) ? cosf((float)s * fr) : sinf((float)s * fr);
            }
            if (RES) v += Res[(size_t)m * N + n];
            if (RELU) v = fmaxf(v, 0.0f);
            op[j] = v;
        }
        *(float4*)&C[(size_t)m * N + n0 + tx * 4] = outv;
    }
}

// ---------------------------------------------------------------- flash attention (fp32), 64 q-rows per block, kv chunks of 64, hd=64
// P buffer aliases the K buffer (3x 17KB LDS keeps static shared < 64KB).
__global__ __launch_bounds__(256) void flash_k(
    const float* __restrict__ Qp, long long q_bs, int q_rs,
    const float* __restrict__ Kp, const float* __restrict__ Vp, long long kv_bs, int kv_rs,
    float* __restrict__ Op, long long o_bs, int skv)
{
    __shared__ float Qs[64][68];
    __shared__ float KPs[64][68];   // K chunk, later reused for P
    __shared__ float Vs[64][68];
    const int qt = blockIdx.x, h = blockIdx.y, b = blockIdx.z;
    const float* Q = Qp + (size_t)b * q_bs + h * 64;
    const float* K = Kp + (size_t)b * kv_bs + h * 64;
    const float* V = Vp + (size_t)b * kv_bs + h * 64;
    float* O = Op + (size_t)b * o_bs + h * 64;
    const int q0 = qt * 64;
    const int tid = threadIdx.x, tx = tid & 15, ty = tid >> 4;

    #pragma unroll
    for (int e = 0; e < 4; ++e) {
        int f = tid + e * 256;
        int r = f >> 4, c4 = (f & 15) << 2;
        float4 v = *(const float4*)&Q[(size_t)(q0 + r) * q_rs + c4];
        v.x *= 0.125f; v.y *= 0.125f; v.z *= 0.125f; v.w *= 0.125f;   // 1/sqrt(hd)
        *(float4*)&Qs[r][c4] = v;
    }

    float m_i[4], l_i[4], o[4][4];
    #pragma unroll
    for (int i = 0; i < 4; ++i) {
        m_i[i] = -INFINITY; l_i[i] = 0.f;
        #pragma unroll
        for (int j = 0; j < 4; ++j) o[i][j] = 0.f;
    }

    for (int kv0 = 0; kv0 < skv; kv0 += 64) {
        __syncthreads();   // prev chunk's P/V reads done (also covers initial Q-load)
        #pragma unroll
        for (int e = 0; e < 4; ++e) {
            int f = tid + e * 256;
            int r = f >> 4, c4 = (f & 15) << 2;
            *(float4*)&KPs[r][c4] = *(const float4*)&K[(size_t)(kv0 + r) * kv_rs + c4];
            *(float4*)&Vs[r][c4]  = *(const float4*)&V[(size_t)(kv0 + r) * kv_rs + c4];
        }
        __syncthreads();
        // scores 64x64: thread (tx,ty) -> rows ty*4+i, kv cols tx*4+j
        float sc[4][4] = {};
        #pragma unroll 4
        for (int d = 0; d < 64; d += 4) {
            float qa[4][4], kb[4][4];
            #pragma unroll
            for (int i = 0; i < 4; ++i) {
                float4 t = *(const float4*)&Qs[ty * 4 + i][d];
                qa[i][0] = t.x; qa[i][1] = t.y; qa[i][2] = t.z; qa[i][3] = t.w;
            }
            #pragma unroll
            for (int j = 0; j < 4; ++j) {
                float4 u = *(const float4*)&KPs[tx * 4 + j][d];
                kb[j][0] = u.x; kb[j][1] = u.y; kb[j][2] = u.z; kb[j][3] = u.w;
            }
            #pragma unroll
            for (int i = 0; i < 4; ++i)
                #pragma unroll
                for (int j = 0; j < 4; ++j)
                    #pragma unroll
                    for (int c = 0; c < 4; ++c)
                        sc[i][j] += qa[i][c] * kb[j][c];
        }
        // online softmax: row stats across the 16 tx lanes (same ty -> contiguous lanes)
        float rmax[4];
        #pragma unroll
        for (int i = 0; i < 4; ++i)
            rmax[i] = fmaxf(fmaxf(sc[i][0], sc[i][1]), fmaxf(sc[i][2], sc[i][3]));
        #pragma unroll
        for (int off = 1; off < 16; off <<= 1)
            #pragma unroll
            for (int i = 0; i < 4; ++i)
                rmax[i] = fmaxf(rmax[i], __shfl_xor(rmax[i], off));
        float alpha[4];
        #pragma unroll
        for (int i = 0; i < 4; ++i) {
            float mn = fmaxf(m_i[i], rmax[i]);
            alpha[i] = __expf(m_i[i] - mn);       // first iter: exp(-inf)=0
            m_i[i] = mn;
        }
        float p[4][4], rsum[4];
        #pragma unroll
        for (int i = 0; i < 4; ++i) {
            rsum[i] = 0.f;
            #pragma unroll
            for (int j = 0; j < 4; ++j) { p[i][j] = __expf(sc[i][j] - m_i[i]); rsum[i] += p[i][j]; }
        }
        #pragma unroll
        for (int off = 1; off < 16; off <<= 1)
            #pragma unroll
            for (int i = 0; i < 4; ++i)
                rsum[i] += __shfl_xor(rsum[i], off);
        #pragma unroll
        for (int i = 0; i < 4; ++i) {
            l_i[i] = l_i[i] * alpha[i] + rsum[i];
            #pragma unroll
            for (int j = 0; j < 4; ++j) o[i][j] *= alpha[i];
        }
        __syncthreads();   // all lanes done reading K before overwriting with P
        #pragma unroll
        for (int i = 0; i < 4; ++i)
            *(float4*)&KPs[ty * 4 + i][tx * 4] = make_float4(p[i][0], p[i][1], p[i][2], p[i][3]);
        __syncthreads();
        // O += P * V : thread (tx,ty) -> rows ty*4+i, d cols tx*4+j
        #pragma unroll 4
        for (int kv = 0; kv < 64; kv += 4) {
            float pa[4][4];
            #pragma unroll
            for (int i = 0; i < 4; ++i) {
                float4 t = *(const float4*)&KPs[ty * 4 + i][kv];
                pa[i][0] = t.x; pa[i][1] = t.y; pa[i][2] = t.z; pa[i][3] = t.w;
            }
            #pragma unroll
            for (int q2 = 0; q2 < 4; ++q2) {
                float4 vv = *(const float4*)&Vs[kv + q2][tx * 4];
                #pragma unroll
                for (int i = 0; i < 4; ++i) {
                    o[i][0] += pa[i][q2] * vv.x;
                    o[i][1] += pa[i][q2] * vv.y;
                    o[i][2] += pa[i][q2] * vv.z;
                    o[i][3] += pa[i][q2] * vv.w;
                }
            }
        }
    }
    #pragma unroll
    for (int i = 0; i < 4; ++i) {
        float inv = 1.0f / l_i[i];
        float4 outv = make_float4(o[i][0] * inv, o[i][1] * inv, o[i][2] * inv, o[i][3] * inv);
        *(float4*)&O[(size_t)(q0 + ty * 4 + i) * kD + tx * 4] = outv;
    }
}

// ---------------------------------------------------------------- layernorm over D=512, one wave per row
__global__ __launch_bounds__(64) void ln_k(const float* __restrict__ X, float* __restrict__ Y,
                                           const float* __restrict__ g, const float* __restrict__ bt)
{
    int row = blockIdx.x, lane = threadIdx.x;
    const float* x = X + (size_t)row * 512;
    int c0 = lane * 4, c1 = 256 + lane * 4;
    float4 a0 = *(const float4*)&x[c0];
    float4 a1 = *(const float4*)&x[c1];
    float s  = a0.x + a0.y + a0.z + a0.w + a1.x + a1.y + a1.z + a1.w;
    float ss = a0.x * a0.x + a0.y * a0.y + a0.z * a0.z + a0.w * a0.w
             + a1.x * a1.x + a1.y * a1.y + a1.z * a1.z + a1.w * a1.w;
    #pragma unroll
    for (int off = 1; off < 64; off <<= 1) { s += __shfl_xor(s, off); ss += __shfl_xor(ss, off); }
    float mean = s * (1.f / 512.f);
    float var  = ss * (1.f / 512.f) - mean * mean;
    float rs = rsqrtf(var + 1e-5f);
    float4 g0 = *(const float4*)&g[c0], g1 = *(const float4*)&g[c1];
    float4 b0 = *(const float4*)&bt[c0], b1 = *(const float4*)&bt[c1];
    float* y = Y + (size_t)row * 512;
    float4 o0, o1;
    o0.x = (a0.x - mean) * rs * g0.x + b0.x;  o0.y = (a0.y - mean) * rs * g0.y + b0.y;
    o0.z = (a0.z - mean) * rs * g0.z + b0.z;  o0.w = (a0.w - mean) * rs * g0.w + b0.w;
    o1.x = (a1.x - mean) * rs * g1.x + b1.x;  o1.y = (a1.y - mean) * rs * g1.y + b1.y;
    o1.z = (a1.z - mean) * rs * g1.z + b1.z;  o1.w = (a1.w - mean) * rs * g1.w + b1.w;
    *(float4*)&y[c0] = o0;
    *(float4*)&y[c1] = o1;
}

// ---------------------------------------------------------------- gather gene embeddings
__global__ __launch_bounds__(128) void gather_k(const float* __restrict__ ge, const int* __restrict__ ids,
                                                float* __restrict__ out)
{
    int gi = blockIdx.x, t = threadIdx.x;
    int id = ids[gi];
    *(float4*)&out[(size_t)gi * 512 + t * 4] = *(const float4*)&ge[(size_t)id * 512 + t * 4];
}

// ---------------------------------------------------------------- fused readout: pred = LN(z)*g+b . ro_w + ro_b
__global__ __launch_bounds__(64) void readout_k(const float* __restrict__ Z,
                                                const float* __restrict__ g, const float* __restrict__ bt,
                                                const float* __restrict__ rw, const float* __restrict__ rb,
                                                float* __restrict__ pred)
{
    int row = blockIdx.x, lane = threadIdx.x;
    const float* zr = Z + (size_t)row * 512;
    int c0 = lane * 4, c1 = 256 + lane * 4;
    float4 a0 = *(const float4*)&zr[c0];
    float4 a1 = *(const float4*)&zr[c1];
    float s  = a0.x + a0.y + a0.z + a0.w + a1.x + a1.y + a1.z + a1.w;
    float ss = a0.x * a0.x + a0.y * a0.y + a0.z * a0.z + a0.w * a0.w
             + a1.x * a1.x + a1.y * a1.y + a1.z * a1.z + a1.w * a1.w;
    #pragma unroll
    for (int off = 1; off < 64; off <<= 1) { s += __shfl_xor(s, off); ss += __shfl_xor(ss, off); }
    float mean = s * (1.f / 512.f);
    float var  = ss * (1.f / 512.f) - mean * mean;
    float rs = rsqrtf(var + 1e-5f);
    float4 g0 = *(const float4*)&g[c0], g1 = *(const float4*)&g[c1];
    float4 b0 = *(const float4*)&bt[c0], b1 = *(const float4*)&bt[c1];
    float4 w0 = *(const float4*)&rw[c0], w1 = *(const float4*)&rw[c1];
    float acc = 0.f;
    acc += ((a0.x - mean) * rs * g0.x + b0.x) * w0.x;
    acc += ((a0.y - mean) * rs * g0.y + b0.y) * w0.y;
    acc += ((a0.z - mean) * rs * g0.z + b0.z) * w0.z;
    acc += ((a0.w - mean) * rs * g0.w + b0.w) * w0.w;
    acc += ((a1.x - mean) * rs * g1.x + b1.x) * w1.x;
    acc += ((a1.y - mean) * rs * g1.y + b1.y) * w1.y;
    acc += ((a1.z - mean) * rs * g1.z + b1.z) * w1.z;
    acc += ((a1.w - mean) * rs * g1.w + b1.w) * w1.w;
    #pragma unroll
    for (int off = 1; off < 64; off <<= 1) acc += __shfl_xor(acc, off);
    if (lane == 0) pred[row] = acc + rb[0];
}

// ---------------------------------------------------------------- launch
extern "C" void kernel_launch(void* const* d_in, const int* in_sizes, int n_in,
                              void* d_out, int out_size, void* d_ws, size_t ws_size,
                              hipStream_t stream)
{
    (void)in_sizes; (void)n_in; (void)out_size; (void)ws_size;
    const float* windows    = (const float*)d_in[0];
    const int*   gene_ids   = (const int*)  d_in[1];
    const float* W_window   = (const float*)d_in[2];
    const float* enc_qkv_w  = (const float*)d_in[3];
    const float* enc_qkv_b  = (const float*)d_in[4];
    const float* enc_out_w  = (const float*)d_in[5];
    const float* enc_out_b  = (const float*)d_in[6];
    const float* enc_ln1_g  = (const float*)d_in[7];
    const float* enc_ln1_b  = (const float*)d_in[8];
    const float* enc_ln2_g  = (const float*)d_in[9];
    const float* enc_ln2_b  = (const float*)d_in[10];
    const float* enc_ff1_w  = (const float*)d_in[11];
    const float* enc_ff1_b  = (const float*)d_in[12];
    const float* enc_ff2_w  = (const float*)d_in[13];
    const float* enc_ff2_b  = (const float*)d_in[14];
    const float* gene_embed = (const float*)d_in[15];
    const float* ca_qkv_w   = (const float*)d_in[16];
    const float* ca_qkv_b   = (const float*)d_in[17];
    const float* ca_out_w   = (const float*)d_in[18];
    const float* ca_out_b   = (const float*)d_in[19];
    const float* ro_ln_g    = (const float*)d_in[20];
    const float* ro_ln_b    = (const float*)d_in[21];
    const float* ro_w       = (const float*)d_in[22];
    const float* ro_b       = (const float*)d_in[23];

    float* pred = (float*)d_out;                       // (B,G)
    float* z    = pred + (size_t)kB * kG;              // (B,G,D)

    // workspace layout (floats): 20M floats = 80 MB total
    float* wsf  = (float*)d_ws;
    const size_t MF = 1u << 20;
    float* bx   = wsf;              // 2M  encoder stream x
    float* bh   = wsf + 2 * MF;     // 2M  LN output
    float* bo   = wsf + 4 * MF;     // 2M  attn output (pre out-proj)
    float* bqkv = wsf + 6 * MF;     // 6M  qkv  | cross: kvc(4M)+qg(1M)+ge(1M)
    float* bbig = wsf + 12 * MF;    // 8M  pooled-windows(4M) / ff(8M) / cross-o(8M)
    float* bkvc = bqkv;
    float* bqg  = bqkv + 4 * MF;
    float* bge  = bqkv + 5 * MF;
    float* bff  = bbig;
    float* bpw  = bbig;
    float* boc  = bbig;

    // 1) pool + window projection + positional encoding
    pool_windows_k<<<4096, 256, 0, stream>>>(windows, bpw);
    gemm64_k<false, false, false, true><<<dim3(kD / 64, kNTOK / 64), 256, 0, stream>>>(
        bpw, W_window, nullptr, nullptr, bx, kNTOK, kD, kWIN);

    // 2) encoder layers
    for (int l = 0; l < kL; ++l) {
        ln_k<<<kNTOK, 64, 0, stream>>>(bx, bh, enc_ln1_g + l * kD, enc_ln1_b + l * kD);
        gemm64_k<true, false, false, false><<<dim3(3 * kD / 64, kNTOK / 64), 256, 0, stream>>>(
            bh, enc_qkv_w + (size_t)l * 3 * kD * kD, enc_qkv_b + l * 3 * kD, nullptr,
            bqkv, kNTOK, 3 * kD, kD);
        flash_k<<<dim3(kS / 64, kNH, kB), 256, 0, stream>>>(
            bqkv, (long long)kS * 3 * kD, 3 * kD,
            bqkv + kD, bqkv + 2 * kD, (long long)kS * 3 * kD, 3 * kD,
            bo, (long long)kS * kD, kS);
        gemm64_k<true, true, false, false><<<dim3(kD / 64, kNTOK / 64), 256, 0, stream>>>(
            bo, enc_out_w + (size_t)l * kD * kD, enc_out_b + l * kD, bx, bx, kNTOK, kD, kD);
        ln_k<<<kNTOK, 64, 0, stream>>>(bx, bh, enc_ln2_g + l * kD, enc_ln2_b + l * kD);
        gemm64_k<true, false, true, false><<<dim3(kDFF / 64, kNTOK / 64), 256, 0, stream>>>(
            bh, enc_ff1_w + (size_t)l * kDFF * kD, enc_ff1_b + l * kDFF, nullptr,
            bff, kNTOK, kDFF, kD);
        gemm64_k<true, true, false, false><<<dim3(kD / 64, kNTOK / 64), 256, 0, stream>>>(
            bff, enc_ff2_w + (size_t)l * kD * kDFF, enc_ff2_b + l * kD, bx, bx, kNTOK, kD, kDFF);
    }

    // 3) cross-attention (Q shared across batch: computed once for G rows)
    gather_k<<<kG, 128, 0, stream>>>(gene_embed, gene_ids, bge);
    gemm64_k<true, false, false, false><<<dim3(kD / 64, kG / 64), 256, 0, stream>>>(
        bge, ca_qkv_w, ca_qkv_b, nullptr, bqg, kG, kD, kD);
    gemm64_k<true, false, false, false><<<dim3(2 * kD / 64, kNTOK / 64), 256, 0, stream>>>(
        bx, ca_qkv_w + kD * kD, ca_qkv_b + kD, nullptr, bkvc, kNTOK, 2 * kD, kD);
    flash_k<<<dim3(kG / 64, kNH, kB), 256, 0, stream>>>(
        bqg, 0LL, kD,
        bkvc, bkvc + kD, (long long)kS * 2 * kD, 2 * kD,
        boc, (long long)kG * kD, kS);
    gemm64_k<true, false, false, false><<<dim3(kD / 64, (kB * kG) / 64), 256, 0, stream>>>(
        boc, ca_out_w, ca_out_b, nullptr, z, kB * kG, kD, kD);

    // 4) readout
    readout_k<<<kB * kG, 64, 0, stream>>>(z, ro_ln_g, ro_ln_b, ro_w, ro_b, pred);
}

// Round 2
// 751.417 us; speedup vs baseline: 3.2223x; 3.2223x over previous
//
#include <hip/hip_runtime.h>
#include <math.h>

// MultiomicTransformer on MI355X — Round 2: bf16 MFMA everywhere.
// B=8 W=2048 WIN=1024 D=512 NH=8 HD=64 DFF=2048 L=4 KS=4 G=2048 S=512

typedef __attribute__((ext_vector_type(8))) short short8v;
typedef __attribute__((ext_vector_type(4))) float float4v;
typedef const __attribute__((address_space(1))) void* gas_t;
typedef __attribute__((address_space(3))) void* las_t;

__device__ inline unsigned short f2bf(float f) {
    unsigned int u = __builtin_bit_cast(unsigned int, f);
    return (unsigned short)((u + 0x7fffu + ((u >> 16) & 1u)) >> 16);   // RNE
}

// ---------------------------------------------------------------- fp32 -> bf16 bulk convert
__global__ __launch_bounds__(256) void cvt_k(const float* __restrict__ src,
                                             unsigned short* __restrict__ dst, int n4)
{
    int i = blockIdx.x * 256 + threadIdx.x;
    if (i >= n4) return;
    float4 v = ((const float4*)src)[i];
    ushort4 o;
    o.x = f2bf(v.x); o.y = f2bf(v.y); o.z = f2bf(v.z); o.w = f2bf(v.w);
    ((ushort4*)dst)[i] = o;
}

// ---------------------------------------------------------------- pool mean-4 (commutes with win-proj), bf16 out
__global__ __launch_bounds__(256) void pool_windows_k(const float* __restrict__ win,
                                                      unsigned short* __restrict__ pw)
{
    int idx = blockIdx.x * 256 + threadIdx.x;     // over 4096 tokens * 256 float4
    int n = idx >> 8, c4 = (idx & 255) << 2;
    const float* base = win + (size_t)n * 4096 + c4;   // b*2048*1024 + s*4*1024 == n*4096
    float4 a = *(const float4*)(base);
    float4 b2 = *(const float4*)(base + 1024);
    float4 c = *(const float4*)(base + 2048);
    float4 d = *(const float4*)(base + 3072);
    ushort4 r;
    r.x = f2bf((a.x + b2.x + c.x + d.x) * 0.25f);
    r.y = f2bf((a.y + b2.y + c.y + d.y) * 0.25f);
    r.z = f2bf((a.z + b2.z + c.z + d.z) * 0.25f);
    r.w = f2bf((a.w + b2.w + c.w + d.w) * 0.25f);
    ((ushort4*)pw)[idx] = r;
}

// ---------------------------------------------------------------- bf16 MFMA GEMM (m97 pattern)
// C[M,N] = A[M,K] * Bw[N,K]^T. 128x128 tile, 256 thr (4 waves, 2x2 of 64x64),
// K-step 32, global_load_lds width 16, fragments = contiguous-8 ds_read_b128.
template<bool BIAS, bool RES, bool RELU, bool POSENC, bool O32, bool O16>
__global__ __launch_bounds__(256) void gemm_bf16_k(
    const unsigned short* __restrict__ A, const unsigned short* __restrict__ Bw,
    const float* __restrict__ bias, const float* __restrict__ Res,
    float* __restrict__ C32, unsigned short* __restrict__ C16,
    int M, int N, int K)
{
    __shared__ __align__(16) unsigned short As[128 * 32];
    __shared__ __align__(16) unsigned short Bs[128 * 32];
    const int tid = threadIdx.x;
    const int lane = tid & 63;
    const int n0 = blockIdx.x * 128, m0 = blockIdx.y * 128;
    const int wr = tid >> 7, wc = (tid >> 6) & 1;          // wave quadrant
    const int c0 = tid, c1 = tid + 256;                    // 16B chunks (512 per operand)
    const unsigned short* gA0 = A + (size_t)(m0 + (c0 >> 2)) * K + (c0 & 3) * 8;
    const unsigned short* gA1 = A + (size_t)(m0 + (c1 >> 2)) * K + (c1 & 3) * 8;
    const unsigned short* gB0 = Bw + (size_t)(n0 + (c0 >> 2)) * K + (c0 & 3) * 8;
    const unsigned short* gB1 = Bw + (size_t)(n0 + (c1 >> 2)) * K + (c1 & 3) * 8;
    const int r = lane & 15, g = lane >> 4;
    const int aoff = (64 * wr + r) * 32 + g * 8;
    const int boff = (64 * wc + r) * 32 + g * 8;

    float4v acc[4][4];
    float4v z4 = {0.f, 0.f, 0.f, 0.f};
    #pragma unroll
    for (int i = 0; i < 4; ++i)
        #pragma unroll
        for (int j = 0; j < 4; ++j) acc[i][j] = z4;

    for (int k0 = 0; k0 < K; k0 += 32) {
        __builtin_amdgcn_global_load_lds((gas_t)(gA0 + k0), (las_t)(&As[c0 * 8]), 16, 0, 0);
        __builtin_amdgcn_global_load_lds((gas_t)(gA1 + k0), (las_t)(&As[c1 * 8]), 16, 0, 0);
        __builtin_amdgcn_global_load_lds((gas_t)(gB0 + k0), (las_t)(&Bs[c0 * 8]), 16, 0, 0);
        __builtin_amdgcn_global_load_lds((gas_t)(gB1 + k0), (las_t)(&Bs[c1 * 8]), 16, 0, 0);
        __syncthreads();
        short8v a[4], b[4];
        #pragma unroll
        for (int mi = 0; mi < 4; ++mi) a[mi] = *(const short8v*)&As[aoff + mi * (16 * 32)];
        #pragma unroll
        for (int ni = 0; ni < 4; ++ni) b[ni] = *(const short8v*)&Bs[boff + ni * (16 * 32)];
        #pragma unroll
        for (int mi = 0; mi < 4; ++mi)
            #pragma unroll
            for (int ni = 0; ni < 4; ++ni)
                acc[mi][ni] = __builtin_amdgcn_mfma_f32_16x16x32_bf16(a[mi], b[ni], acc[mi][ni], 0, 0, 0);
        __syncthreads();
    }

    #pragma unroll
    for (int mi = 0; mi < 4; ++mi) {
        #pragma unroll
        for (int ni = 0; ni < 4; ++ni) {
            const int row0 = m0 + 64 * wr + 16 * mi + g * 4;
            const int col  = n0 + 64 * wc + 16 * ni + r;
            float bv = BIAS ? bias[col] : 0.f;
            float fr = 0.f;
            if (POSENC) fr = __expf((float)(col & ~1) * -0.01798894600f);  // exp(-2i*ln(1e4)/512)
            #pragma unroll
            for (int q = 0; q < 4; ++q) {
                const int row = row0 + q;
                float v = acc[mi][ni][q] + bv;
                if (POSENC) {
                    float ang = (float)(row & 511) * fr;
                    v += (col & 1) ? __cosf(ang) : __sinf(ang);
                }
                if (RES) v += Res[(size_t)row * N + col];
                if (RELU) v = fmaxf(v, 0.f);
                if (O32) C32[(size_t)row * N + col] = v;
                if (O16) C16[(size_t)row * N + col] = f2bf(v);
            }
        }
    }
}

// ---------------------------------------------------------------- MFMA flash attention, bf16 in/out, hd=64
// 256 thr = 4 waves x 16 q-rows; kv chunks of 64; online softmax in fp32.
__global__ __launch_bounds__(256) void flashb_k(
    const unsigned short* __restrict__ Qp, long long q_bs, int q_rs,
    const unsigned short* __restrict__ Kp, const unsigned short* __restrict__ Vp,
    long long kv_bs, int kv_rs,
    unsigned short* __restrict__ Op, long long o_bs, int o_rs, int skv)
{
    __shared__ __align__(16) unsigned short Qs[64 * 72];
    __shared__ __align__(16) unsigned short Ks[64 * 72];
    __shared__ __align__(16) unsigned short Ps[64 * 72];
    __shared__ __align__(16) unsigned short Vt[64 * 72];   // Vt[d][kv]
    const int qt = blockIdx.x, h = blockIdx.y, b = blockIdx.z;
    const unsigned short* Q = Qp + (size_t)b * q_bs + h * 64;
    const unsigned short* K = Kp + (size_t)b * kv_bs + h * 64;
    const unsigned short* V = Vp + (size_t)b * kv_bs + h * 64;
    unsigned short* O = Op + (size_t)b * o_bs + h * 64;
    const int q0 = qt * 64;
    const int tid = threadIdx.x;
    const int lane = tid & 63, w = tid >> 6;
    const int r = lane & 15, g = lane >> 4;

    #pragma unroll
    for (int e = 0; e < 2; ++e) {        // stage Q (64x64 bf16)
        int c = tid + e * 256;
        int row = c >> 3, sub = c & 7;
        *(uint4*)&Qs[row * 72 + sub * 8] = *(const uint4*)&Q[(size_t)(q0 + row) * q_rs + sub * 8];
    }

    float4v acc_o[4];
    float4v z4 = {0.f, 0.f, 0.f, 0.f};
    #pragma unroll
    for (int dt = 0; dt < 4; ++dt) acc_o[dt] = z4;
    float m_i[4], l_i[4];
    #pragma unroll
    for (int q = 0; q < 4; ++q) { m_i[q] = -INFINITY; l_i[q] = 0.f; }

    for (int kv0 = 0; kv0 < skv; kv0 += 64) {
        __syncthreads();                  // prev PV reads done (also covers Q stage, iter 0)
        #pragma unroll
        for (int e = 0; e < 2; ++e) {     // stage K row-major
            int c = tid + e * 256;
            int row = c >> 3, sub = c & 7;
            *(uint4*)&Ks[row * 72 + sub * 8] = *(const uint4*)&K[(size_t)(kv0 + row) * kv_rs + sub * 8];
        }
        #pragma unroll
        for (int e = 0; e < 2; ++e) {     // stage V transposed: Vt[d][kv]
            int c = tid + e * 256;
            int row = c >> 3, d0 = (c & 7) * 8;
            uint4 vv = *(const uint4*)&V[(size_t)(kv0 + row) * kv_rs + d0];
            unsigned int uu[4] = {vv.x, vv.y, vv.z, vv.w};
            #pragma unroll
            for (int i = 0; i < 4; ++i) {
                Vt[(d0 + 2 * i) * 72 + row]     = (unsigned short)(uu[i] & 0xffffu);
                Vt[(d0 + 2 * i + 1) * 72 + row] = (unsigned short)(uu[i] >> 16);
            }
        }
        __syncthreads();

        // S = (Q K^T) * 1/8 : wave strip 16q x 64kv, 8 MFMA
        short8v aq0 = *(const short8v*)&Qs[(16 * w + r) * 72 + g * 8];
        short8v aq1 = *(const short8v*)&Qs[(16 * w + r) * 72 + 32 + g * 8];
        float4v accs[4];
        #pragma unroll
        for (int t = 0; t < 4; ++t) accs[t] = z4;
        #pragma unroll
        for (int t = 0; t < 4; ++t) {
            short8v bk0 = *(const short8v*)&Ks[(16 * t + r) * 72 + g * 8];
            short8v bk1 = *(const short8v*)&Ks[(16 * t + r) * 72 + 32 + g * 8];
            accs[t] = __builtin_amdgcn_mfma_f32_16x16x32_bf16(aq0, bk0, accs[t], 0, 0, 0);
            accs[t] = __builtin_amdgcn_mfma_f32_16x16x32_bf16(aq1, bk1, accs[t], 0, 0, 0);
        }

        // online softmax, rows = g*4+q, kv cols = r+16t; reduce across 16-lane groups
        float sv[4][4];
        #pragma unroll
        for (int t = 0; t < 4; ++t)
            #pragma unroll
            for (int q = 0; q < 4; ++q) sv[t][q] = accs[t][q] * 0.125f;
        float rmax[4];
        #pragma unroll
        for (int q = 0; q < 4; ++q)
            rmax[q] = fmaxf(fmaxf(sv[0][q], sv[1][q]), fmaxf(sv[2][q], sv[3][q]));
        #pragma unroll
        for (int off = 1; off < 16; off <<= 1)
            #pragma unroll
            for (int q = 0; q < 4; ++q) rmax[q] = fmaxf(rmax[q], __shfl_xor(rmax[q], off));
        float alpha[4];
        #pragma unroll
        for (int q = 0; q < 4; ++q) {
            float mn = fmaxf(m_i[q], rmax[q]);
            alpha[q] = __expf(m_i[q] - mn);    // first chunk: exp(-inf)=0
            m_i[q] = mn;
        }
        float rsum[4] = {0.f, 0.f, 0.f, 0.f};
        #pragma unroll
        for (int t = 0; t < 4; ++t)
            #pragma unroll
            for (int q = 0; q < 4; ++q) { float p = __expf(sv[t][q] - m_i[q]); sv[t][q] = p; rsum[q] += p; }
        #pragma unroll
        for (int off = 1; off < 16; off <<= 1)
            #pragma unroll
            for (int q = 0; q < 4; ++q) rsum[q] += __shfl_xor(rsum[q], off);
        #pragma unroll
        for (int q = 0; q < 4; ++q) l_i[q] = l_i[q] * alpha[q] + rsum[q];

        // write P strip (wave-private rows 16w..16w+15), bf16
        #pragma unroll
        for (int t = 0; t < 4; ++t)
            #pragma unroll
            for (int q = 0; q < 4; ++q)
                Ps[(16 * w + g * 4 + q) * 72 + t * 16 + r] = f2bf(sv[t][q]);
        __syncthreads();                  // P writes drained; K reads done

        // O = diag(alpha)*O + P V : per wave 16q x 64d, 8 MFMA
        #pragma unroll
        for (int dt = 0; dt < 4; ++dt)
            #pragma unroll
            for (int q = 0; q < 4; ++q) acc_o[dt][q] *= alpha[q];
        short8v pa0 = *(const short8v*)&Ps[(16 * w + r) * 72 + g * 8];
        short8v pa1 = *(const short8v*)&Ps[(16 * w + r) * 72 + 32 + g * 8];
        #pragma unroll
        for (int dt = 0; dt < 4; ++dt) {
            short8v bv0 = *(const short8v*)&Vt[(16 * dt + r) * 72 + g * 8];
            short8v bv1 = *(const short8v*)&Vt[(16 * dt + r) * 72 + 32 + g * 8];
            acc_o[dt] = __builtin_amdgcn_mfma_f32_16x16x32_bf16(pa0, bv0, acc_o[dt], 0, 0, 0);
            acc_o[dt] = __builtin_amdgcn_mfma_f32_16x16x32_bf16(pa1, bv1, acc_o[dt], 0, 0, 0);
        }
    }

    #pragma unroll
    for (int dt = 0; dt < 4; ++dt)
        #pragma unroll
        for (int q = 0; q < 4; ++q) {
            float v = acc_o[dt][q] / l_i[q];
            O[(size_t)(q0 + 16 * w + g * 4 + q) * o_rs + 16 * dt + r] = f2bf(v);
        }
}

// ---------------------------------------------------------------- layernorm D=512, fp32 in -> bf16 out
__global__ __launch_bounds__(64) void ln_k(const float* __restrict__ X, unsigned short* __restrict__ Y,
                                           const float* __restrict__ g, const float* __restrict__ bt)
{
    int row = blockIdx.x, lane = threadIdx.x;
    const float* x = X + (size_t)row * 512;
    int c0 = lane * 4, c1 = 256 + lane * 4;
    float4 a0 = *(const float4*)&x[c0];
    float4 a1 = *(const float4*)&x[c1];
    float s  = a0.x + a0.y + a0.z + a0.w + a1.x + a1.y + a1.z + a1.w;
    float ss = a0.x * a0.x + a0.y * a0.y + a0.z * a0.z + a0.w * a0.w
             + a1.x * a1.x + a1.y * a1.y + a1.z * a1.z + a1.w * a1.w;
    #pragma unroll
    for (int off = 1; off < 64; off <<= 1) { s += __shfl_xor(s, off); ss += __shfl_xor(ss, off); }
    float mean = s * (1.f / 512.f);
    float var  = ss * (1.f / 512.f) - mean * mean;
    float rs = rsqrtf(var + 1e-5f);
    float4 g0 = *(const float4*)&g[c0], g1 = *(const float4*)&g[c1];
    float4 b0 = *(const float4*)&bt[c0], b1 = *(const float4*)&bt[c1];
    unsigned short* y = Y + (size_t)row * 512;
    ushort4 o0, o1;
    o0.x = f2bf((a0.x - mean) * rs * g0.x + b0.x);  o0.y = f2bf((a0.y - mean) * rs * g0.y + b0.y);
    o0.z = f2bf((a0.z - mean) * rs * g0.z + b0.z);  o0.w = f2bf((a0.w - mean) * rs * g0.w + b0.w);
    o1.x = f2bf((a1.x - mean) * rs * g1.x + b1.x);  o1.y = f2bf((a1.y - mean) * rs * g1.y + b1.y);
    o1.z = f2bf((a1.z - mean) * rs * g1.z + b1.z);  o1.w = f2bf((a1.w - mean) * rs * g1.w + b1.w);
    *(ushort4*)&y[c0] = o0;
    *(ushort4*)&y[c1] = o1;
}

// ---------------------------------------------------------------- gather gene embeddings -> bf16
__global__ __launch_bounds__(128) void gather_k(const float* __restrict__ ge, const int* __restrict__ ids,
                                                unsigned short* __restrict__ out)
{
    int gi = blockIdx.x, t = threadIdx.x;
    int id = ids[gi];
    float4 v = *(const float4*)&ge[(size_t)id * 512 + t * 4];
    ushort4 o;
    o.x = f2bf(v.x); o.y = f2bf(v.y); o.z = f2bf(v.z); o.w = f2bf(v.w);
    *(ushort4*)&out[(size_t)gi * 512 + t * 4] = o;
}

// ---------------------------------------------------------------- fused readout: pred = LN(z)*g+b . ro_w + ro_b
__global__ __launch_bounds__(64) void readout_k(const float* __restrict__ Z,
                                                const float* __restrict__ g, const float* __restrict__ bt,
                                                const float* __restrict__ rw, const float* __restrict__ rb,
                                                float* __restrict__ pred)
{
    int row = blockIdx.x, lane = threadIdx.x;
    const float* zr = Z + (size_t)row * 512;
    int c0 = lane * 4, c1 = 256 + lane * 4;
    float4 a0 = *(const float4*)&zr[c0];
    float4 a1 = *(const float4*)&zr[c1];
    float s  = a0.x + a0.y + a0.z + a0.w + a1.x + a1.y + a1.z + a1.w;
    float ss = a0.x * a0.x + a0.y * a0.y + a0.z * a0.z + a0.w * a0.w
             + a1.x * a1.x + a1.y * a1.y + a1.z * a1.z + a1.w * a1.w;
    #pragma unroll
    for (int off = 1; off < 64; off <<= 1) { s += __shfl_xor(s, off); ss += __shfl_xor(ss, off); }
    float mean = s * (1.f / 512.f);
    float var  = ss * (1.f / 512.f) - mean * mean;
    float rs = rsqrtf(var + 1e-5f);
    float4 g0 = *(const float4*)&g[c0], g1 = *(const float4*)&g[c1];
    float4 b0 = *(const float4*)&bt[c0], b1 = *(const float4*)&bt[c1];
    float4 w0 = *(const float4*)&rw[c0], w1 = *(const float4*)&rw[c1];
    float acc = 0.f;
    acc += ((a0.x - mean) * rs * g0.x + b0.x) * w0.x;
    acc += ((a0.y - mean) * rs * g0.y + b0.y) * w0.y;
    acc += ((a0.z - mean) * rs * g0.z + b0.z) * w0.z;
    acc += ((a0.w - mean) * rs * g0.w + b0.w) * w0.w;
    acc += ((a1.x - mean) * rs * g1.x + b1.x) * w1.x;
    acc += ((a1.y - mean) * rs * g1.y + b1.y) * w1.y;
    acc += ((a1.z - mean) * rs * g1.z + b1.z) * w1.z;
    acc += ((a1.w - mean) * rs * g1.w + b1.w) * w1.w;
    #pragma unroll
    for (int off = 1; off < 64; off <<= 1) acc += __shfl_xor(acc, off);
    if (lane == 0) pred[row] = acc + rb[0];
}

// ---------------------------------------------------------------- launch
extern "C" void kernel_launch(void* const* d_in, const int* in_sizes, int n_in,
                              void* d_out, int out_size, void* d_ws, size_t ws_size,
                              hipStream_t stream)
{
    (void)in_sizes; (void)n_in; (void)out_size; (void)ws_size;
    const float* windows    = (const float*)d_in[0];
    const int*   gene_ids   = (const int*)  d_in[1];
    const float* W_window   = (const float*)d_in[2];
    const float* enc_qkv_w  = (const float*)d_in[3];
    const float* enc_qkv_b  = (const float*)d_in[4];
    const float* enc_out_w  = (const float*)d_in[5];
    const float* enc_out_b  = (const float*)d_in[6];
    const float* enc_ln1_g  = (const float*)d_in[7];
    const float* enc_ln1_b  = (const float*)d_in[8];
    const float* enc_ln2_g  = (const float*)d_in[9];
    const float* enc_ln2_b  = (const float*)d_in[10];
    const float* enc_ff1_w  = (const float*)d_in[11];
    const float* enc_ff1_b  = (const float*)d_in[12];
    const float* enc_ff2_w  = (const float*)d_in[13];
    const float* enc_ff2_b  = (const float*)d_in[14];
    const float* gene_embed = (const float*)d_in[15];
    const float* ca_qkv_w   = (const float*)d_in[16];
    const float* ca_qkv_b   = (const float*)d_in[17];
    const float* ca_out_w   = (const float*)d_in[18];
    const float* ca_out_b   = (const float*)d_in[19];
    const float* ro_ln_g    = (const float*)d_in[20];
    const float* ro_ln_b    = (const float*)d_in[21];
    const float* ro_w       = (const float*)d_in[22];
    const float* ro_b       = (const float*)d_in[23];

    float* pred = (float*)d_out;
    float* z    = pred + (size_t)8 * 2048;

    // workspace carve-up (75 MB total)
    char* wp = (char*)d_ws;
    float* x = (float*)wp;                      wp += (size_t)4096 * 512 * 4;   // 8 MB
    unsigned short* x16   = (unsigned short*)wp; wp += (size_t)4096 * 512 * 2;  // 4 MB
    unsigned short* h16   = (unsigned short*)wp; wp += (size_t)4096 * 512 * 2;  // 4 MB
    unsigned short* qkv16 = (unsigned short*)wp; wp += (size_t)4096 * 1536 * 2; // 12 MB
    unsigned short* ao16  = (unsigned short*)wp; wp += (size_t)4096 * 512 * 2;  // 4 MB
    unsigned short* big16 = (unsigned short*)wp; wp += (size_t)16384 * 512 * 2; // 16 MB
    unsigned short* wW16    = (unsigned short*)wp; wp += (size_t)512 * 1024 * 2;
    unsigned short* wqkv16  = (unsigned short*)wp; wp += (size_t)4 * 1536 * 512 * 2;
    unsigned short* wout16  = (unsigned short*)wp; wp += (size_t)4 * 512 * 512 * 2;
    unsigned short* wff116  = (unsigned short*)wp; wp += (size_t)4 * 2048 * 512 * 2;
    unsigned short* wff216  = (unsigned short*)wp; wp += (size_t)4 * 512 * 2048 * 2;
    unsigned short* wcaqkv16 = (unsigned short*)wp; wp += (size_t)1536 * 512 * 2;
    unsigned short* wcaout16 = (unsigned short*)wp; wp += (size_t)512 * 512 * 2;
    // aliases into big16 / qkv16 (lifetimes disjoint)
    unsigned short* pw16  = big16;                       // 4096x1024
    unsigned short* ff116 = big16;                       // 4096x2048
    unsigned short* oc16  = big16;                       // 16384x512
    unsigned short* ge16  = qkv16;                       // 2048x512
    unsigned short* qg16  = qkv16 + (size_t)2048 * 512;  // 2048x512
    unsigned short* kv16  = qkv16 + (size_t)2 * 2048 * 512; // 4096x1024

    auto cvt = [&](const float* s, unsigned short* d, int n) {
        cvt_k<<<(n / 4 + 255) / 256, 256, 0, stream>>>(s, d, n / 4);
    };
    cvt(W_window,  wW16,    512 * 1024);
    cvt(enc_qkv_w, wqkv16,  4 * 1536 * 512);
    cvt(enc_out_w, wout16,  4 * 512 * 512);
    cvt(enc_ff1_w, wff116,  4 * 2048 * 512);
    cvt(enc_ff2_w, wff216,  4 * 512 * 2048);
    cvt(ca_qkv_w,  wcaqkv16, 1536 * 512);
    cvt(ca_out_w,  wcaout16, 512 * 512);

    // 1) pool + window projection + posenc -> x (fp32)
    pool_windows_k<<<4096, 256, 0, stream>>>(windows, pw16);
    gemm_bf16_k<false, false, false, true, true, false><<<dim3(4, 32), 256, 0, stream>>>(
        pw16, wW16, nullptr, nullptr, x, nullptr, 4096, 512, 1024);

    // 2) encoder layers
    for (int l = 0; l < 4; ++l) {
        ln_k<<<4096, 64, 0, stream>>>(x, h16, enc_ln1_g + l * 512, enc_ln1_b + l * 512);
        gemm_bf16_k<true, false, false, false, false, true><<<dim3(12, 32), 256, 0, stream>>>(
            h16, wqkv16 + (size_t)l * 1536 * 512, enc_qkv_b + l * 1536, nullptr,
            nullptr, qkv16, 4096, 1536, 512);
        flashb_k<<<dim3(8, 8, 8), 256, 0, stream>>>(
            qkv16, (long long)512 * 1536, 1536,
            qkv16 + 512, qkv16 + 1024, (long long)512 * 1536, 1536,
            ao16, (long long)512 * 512, 512, 512);
        gemm_bf16_k<true, true, false, false, true, false><<<dim3(4, 32), 256, 0, stream>>>(
            ao16, wout16 + (size_t)l * 512 * 512, enc_out_b + l * 512, x, x, nullptr, 4096, 512, 512);
        ln_k<<<4096, 64, 0, stream>>>(x, h16, enc_ln2_g + l * 512, enc_ln2_b + l * 512);
        gemm_bf16_k<true, false, true, false, false, true><<<dim3(16, 32), 256, 0, stream>>>(
            h16, wff116 + (size_t)l * 2048 * 512, enc_ff1_b + l * 2048, nullptr,
            nullptr, ff116, 4096, 2048, 512);
        if (l == 3)
            gemm_bf16_k<true, true, false, false, true, true><<<dim3(4, 32), 256, 0, stream>>>(
                ff116, wff216 + (size_t)l * 512 * 2048, enc_ff2_b + l * 512, x, x, x16, 4096, 512, 2048);
        else
            gemm_bf16_k<true, true, false, false, true, false><<<dim3(4, 32), 256, 0, stream>>>(
                ff116, wff216 + (size_t)l * 512 * 2048, enc_ff2_b + l * 512, x, x, nullptr, 4096, 512, 2048);
    }

    // 3) cross-attention
    gather_k<<<2048, 128, 0, stream>>>(gene_embed, gene_ids, ge16);
    gemm_bf16_k<true, false, false, false, false, true><<<dim3(4, 16), 256, 0, stream>>>(
        ge16, wcaqkv16, ca_qkv_b, nullptr, nullptr, qg16, 2048, 512, 512);
    gemm_bf16_k<true, false, false, false, false, true><<<dim3(8, 32), 256, 0, stream>>>(
        x16, wcaqkv16 + (size_t)512 * 512, ca_qkv_b + 512, nullptr, nullptr, kv16, 4096, 1024, 512);
    flashb_k<<<dim3(32, 8, 8), 256, 0, stream>>>(
        qg16, 0LL, 512,
        kv16, kv16 + 512, (long long)512 * 1024, 1024,
        oc16, (long long)2048 * 512, 512, 512);
    gemm_bf16_k<true, false, false, false, true, false><<<dim3(4, 128), 256, 0, stream>>>(
        oc16, wcaout16, ca_out_b, nullptr, z, nullptr, 16384, 512, 512);

    // 4) readout
    readout_k<<<16384, 64, 0, stream>>>(z, ro_ln_g, ro_ln_b, ro_w, ro_b, pred);
}

// Round 3
// 714.637 us; speedup vs baseline: 3.3881x; 1.0515x over previous
//
#include <hip/hip_runtime.h>
#include <math.h>

// MultiomicTransformer on MI355X — Round 3: flash rebuilt (swapped QK^T, pre-transposed V).
// B=8 W=2048 WIN=1024 D=512 NH=8 HD=64 DFF=2048 L=4 KS=4 G=2048 S=512

typedef __attribute__((ext_vector_type(8))) short short8v;
typedef __attribute__((ext_vector_type(4))) float float4v;
typedef const __attribute__((address_space(1))) void* gas_t;
typedef __attribute__((address_space(3))) void* las_t;

__device__ inline unsigned short f2bf(float f) {
    unsigned int u = __builtin_bit_cast(unsigned int, f);
    return (unsigned short)((u + 0x7fffu + ((u >> 16) & 1u)) >> 16);   // RNE
}

// ---------------------------------------------------------------- fp32 -> bf16 bulk convert
__global__ __launch_bounds__(256) void cvt_k(const float* __restrict__ src,
                                             unsigned short* __restrict__ dst, int n4)
{
    int i = blockIdx.x * 256 + threadIdx.x;
    if (i >= n4) return;
    float4 v = ((const float4*)src)[i];
    ushort4 o;
    o.x = f2bf(v.x); o.y = f2bf(v.y); o.z = f2bf(v.z); o.w = f2bf(v.w);
    ((ushort4*)dst)[i] = o;
}

// ---------------------------------------------------------------- pool mean-4 (commutes with win-proj), bf16 out
__global__ __launch_bounds__(256) void pool_windows_k(const float* __restrict__ win,
                                                      unsigned short* __restrict__ pw)
{
    int idx = blockIdx.x * 256 + threadIdx.x;
    int n = idx >> 8, c4 = (idx & 255) << 2;
    const float* base = win + (size_t)n * 4096 + c4;
    float4 a = *(const float4*)(base);
    float4 b2 = *(const float4*)(base + 1024);
    float4 c = *(const float4*)(base + 2048);
    float4 d = *(const float4*)(base + 3072);
    ushort4 r;
    r.x = f2bf((a.x + b2.x + c.x + d.x) * 0.25f);
    r.y = f2bf((a.y + b2.y + c.y + d.y) * 0.25f);
    r.z = f2bf((a.z + b2.z + c.z + d.z) * 0.25f);
    r.w = f2bf((a.w + b2.w + c.w + d.w) * 0.25f);
    ((ushort4*)pw)[idx] = r;
}

// ---------------------------------------------------------------- bf16 MFMA GEMM (m97 pattern)
// C[M,N] = A[M,K] * Bw[N,K]^T. 128x128 tile, 4 waves (2x2 of 64x64), K-step 32.
// BROW: bias indexed by output ROW (for the V^T = Wv*h^T transposed GEMMs).
template<bool BIAS, bool BROW, bool RES, bool RELU, bool POSENC, bool O32, bool O16>
__global__ __launch_bounds__(256) void gemm_bf16_k(
    const unsigned short* __restrict__ A, const unsigned short* __restrict__ Bw,
    const float* __restrict__ bias, const float* __restrict__ Res,
    float* __restrict__ C32, unsigned short* __restrict__ C16,
    int M, int N, int K)
{
    __shared__ __align__(16) unsigned short As[128 * 32];
    __shared__ __align__(16) unsigned short Bs[128 * 32];
    const int tid = threadIdx.x;
    const int lane = tid & 63;
    const int n0 = blockIdx.x * 128, m0 = blockIdx.y * 128;
    const int wr = tid >> 7, wc = (tid >> 6) & 1;
    const int c0 = tid, c1 = tid + 256;
    const unsigned short* gA0 = A + (size_t)(m0 + (c0 >> 2)) * K + (c0 & 3) * 8;
    const unsigned short* gA1 = A + (size_t)(m0 + (c1 >> 2)) * K + (c1 & 3) * 8;
    const unsigned short* gB0 = Bw + (size_t)(n0 + (c0 >> 2)) * K + (c0 & 3) * 8;
    const unsigned short* gB1 = Bw + (size_t)(n0 + (c1 >> 2)) * K + (c1 & 3) * 8;
    const int r = lane & 15, g = lane >> 4;
    const int aoff = (64 * wr + r) * 32 + g * 8;
    const int boff = (64 * wc + r) * 32 + g * 8;

    float4v acc[4][4];
    float4v z4 = {0.f, 0.f, 0.f, 0.f};
    #pragma unroll
    for (int i = 0; i < 4; ++i)
        #pragma unroll
        for (int j = 0; j < 4; ++j) acc[i][j] = z4;

    for (int k0 = 0; k0 < K; k0 += 32) {
        __builtin_amdgcn_global_load_lds((gas_t)(gA0 + k0), (las_t)(&As[c0 * 8]), 16, 0, 0);
        __builtin_amdgcn_global_load_lds((gas_t)(gA1 + k0), (las_t)(&As[c1 * 8]), 16, 0, 0);
        __builtin_amdgcn_global_load_lds((gas_t)(gB0 + k0), (las_t)(&Bs[c0 * 8]), 16, 0, 0);
        __builtin_amdgcn_global_load_lds((gas_t)(gB1 + k0), (las_t)(&Bs[c1 * 8]), 16, 0, 0);
        __syncthreads();
        short8v a[4], b[4];
        #pragma unroll
        for (int mi = 0; mi < 4; ++mi) a[mi] = *(const short8v*)&As[aoff + mi * (16 * 32)];
        #pragma unroll
        for (int ni = 0; ni < 4; ++ni) b[ni] = *(const short8v*)&Bs[boff + ni * (16 * 32)];
        #pragma unroll
        for (int mi = 0; mi < 4; ++mi)
            #pragma unroll
            for (int ni = 0; ni < 4; ++ni)
                acc[mi][ni] = __builtin_amdgcn_mfma_f32_16x16x32_bf16(a[mi], b[ni], acc[mi][ni], 0, 0, 0);
        __syncthreads();
    }

    #pragma unroll
    for (int mi = 0; mi < 4; ++mi) {
        #pragma unroll
        for (int ni = 0; ni < 4; ++ni) {
            const int row0 = m0 + 64 * wr + 16 * mi + g * 4;
            const int col  = n0 + 64 * wc + 16 * ni + r;
            float bv = (BIAS && !BROW) ? bias[col] : 0.f;
            float fr = 0.f;
            if (POSENC) fr = __expf((float)(col & ~1) * -0.01798894600f);
            #pragma unroll
            for (int q = 0; q < 4; ++q) {
                const int row = row0 + q;
                float v = acc[mi][ni][q] + bv;
                if (BIAS && BROW) v += bias[row];
                if (POSENC) {
                    float ang = (float)(row & 511) * fr;
                    v += (col & 1) ? __cosf(ang) : __sinf(ang);
                }
                if (RES) v += Res[(size_t)row * N + col];
                if (RELU) v = fmaxf(v, 0.f);
                if (O32) C32[(size_t)row * N + col] = v;
                if (O16) C16[(size_t)row * N + col] = f2bf(v);
            }
        }
    }
}

// ---------------------------------------------------------------- flash attention, bf16, hd=64
// 4 waves x 16 q-rows; kv chunks of 64; swapped QK^T (P lane-local in kv),
// V pre-transposed in global (Vt[dcol][token]); Q frags direct from global.
__global__ __launch_bounds__(256) void flashb_k(
    const unsigned short* __restrict__ Qp, long long q_bs, int q_rs,
    const unsigned short* __restrict__ Kp, long long k_bs, int k_rs,
    const unsigned short* __restrict__ Vtp, long long v_hs, long long v_bs, int v_rs,
    unsigned short* __restrict__ Op, long long o_bs, int o_rs, int skv)
{
    __shared__ __align__(16) unsigned short Ks[64 * 72];
    __shared__ __align__(16) unsigned short Vs[64 * 72];
    __shared__ __align__(16) unsigned short Ps[64 * 72];
    const int qt = blockIdx.x, h = blockIdx.y, b = blockIdx.z;
    const unsigned short* Q  = Qp  + (size_t)b * q_bs + (size_t)h * 64;
    const unsigned short* K  = Kp  + (size_t)b * k_bs + (size_t)h * 64;
    const unsigned short* Vt = Vtp + (size_t)h * v_hs + (size_t)b * v_bs;
    unsigned short* O = Op + (size_t)b * o_bs + (size_t)h * 64;
    const int q0 = qt * 64;
    const int tid = threadIdx.x, lane = tid & 63, w = tid >> 6;
    const int r = lane & 15, g = lane >> 4;

    // Q B-fragments (per-wave constants): rows 16w+r, k-slice g*8 (+32)
    const unsigned short* qrow = Q + (size_t)(q0 + 16 * w + r) * q_rs + g * 8;
    short8v qf0 = *(const short8v*)(qrow);
    short8v qf1 = *(const short8v*)(qrow + 32);

    // staging coords: thread covers rows sr0 and sr0+32, 8 cols at sc0
    const int sr0 = tid >> 3, sr1 = sr0 + 32, sc0 = (tid & 7) * 8;
    const unsigned short* Krow0 = K + (size_t)sr0 * k_rs + sc0;
    const unsigned short* Krow1 = K + (size_t)sr1 * k_rs + sc0;
    const unsigned short* Vrow0 = Vt + (size_t)sr0 * v_rs + sc0;
    const unsigned short* Vrow1 = Vt + (size_t)sr1 * v_rs + sc0;

    uint4 pk0 = *(const uint4*)(Krow0);
    uint4 pk1 = *(const uint4*)(Krow1);
    uint4 pv0 = *(const uint4*)(Vrow0);
    uint4 pv1 = *(const uint4*)(Vrow1);

    float4v acc_o[4];
    float4v z4 = {0.f, 0.f, 0.f, 0.f};
    #pragma unroll
    for (int dt = 0; dt < 4; ++dt) acc_o[dt] = z4;
    float m_own = -INFINITY, l_own = 0.f;

    for (int kv0 = 0; kv0 < skv; kv0 += 64) {
        __syncthreads();                     // all waves done reading prev Ks/Vs
        *(uint4*)&Ks[sr0 * 72 + sc0] = pk0;
        *(uint4*)&Ks[sr1 * 72 + sc0] = pk1;
        *(uint4*)&Vs[sr0 * 72 + sc0] = pv0;
        *(uint4*)&Vs[sr1 * 72 + sc0] = pv1;
        __syncthreads();
        const int kvn = kv0 + 64;
        if (kvn < skv) {                     // prefetch next chunk (hides HBM under compute)
            pk0 = *(const uint4*)(Krow0 + (size_t)kvn * k_rs);
            pk1 = *(const uint4*)(Krow1 + (size_t)kvn * k_rs);
            pv0 = *(const uint4*)(Vrow0 + kvn);
            pv1 = *(const uint4*)(Vrow1 + kvn);
        }

        // swapped QK^T: out rows = kv, cols = q -> lane holds S[q=r][kv=16t+g*4+reg]
        float4v accs[4];
        #pragma unroll
        for (int t = 0; t < 4; ++t) {
            accs[t] = z4;
            short8v kf0 = *(const short8v*)&Ks[(16 * t + r) * 72 + g * 8];
            short8v kf1 = *(const short8v*)&Ks[(16 * t + r) * 72 + 32 + g * 8];
            accs[t] = __builtin_amdgcn_mfma_f32_16x16x32_bf16(kf0, qf0, accs[t], 0, 0, 0);
            accs[t] = __builtin_amdgcn_mfma_f32_16x16x32_bf16(kf1, qf1, accs[t], 0, 0, 0);
        }

        // online softmax (scale 1/8 folded into exp arg); reduce over lanes sharing l&15
        float sm = -INFINITY;
        #pragma unroll
        for (int t = 0; t < 4; ++t)
            #pragma unroll
            for (int j = 0; j < 4; ++j) sm = fmaxf(sm, accs[t][j]);
        sm = fmaxf(sm, __shfl_xor(sm, 16));
        sm = fmaxf(sm, __shfl_xor(sm, 32));
        float mn = fmaxf(m_own, sm);
        float alpha = __expf(0.125f * (m_own - mn));   // first chunk: exp(-inf)=0
        m_own = mn;
        float p[4][4];
        float rsum = 0.f;
        #pragma unroll
        for (int t = 0; t < 4; ++t)
            #pragma unroll
            for (int j = 0; j < 4; ++j) { p[t][j] = __expf(0.125f * (accs[t][j] - mn)); rsum += p[t][j]; }
        rsum += __shfl_xor(rsum, 16);
        rsum += __shfl_xor(rsum, 32);
        l_own = l_own * alpha + rsum;

        // P write: 4 consecutive kv per reg-quad -> ds_write_b64, wave-private rows
        #pragma unroll
        for (int t = 0; t < 4; ++t) {
            uint2 uu;
            uu.x = (unsigned)f2bf(p[t][0]) | ((unsigned)f2bf(p[t][1]) << 16);
            uu.y = (unsigned)f2bf(p[t][2]) | ((unsigned)f2bf(p[t][3]) << 16);
            *(uint2*)&Ps[(16 * w + r) * 72 + 16 * t + g * 4] = uu;
        }

        // redistribute alpha to O-layout lanes (q = g*4+reg) and rescale O
        float a0_ = __shfl(alpha, g * 4 + 0);
        float a1_ = __shfl(alpha, g * 4 + 1);
        float a2_ = __shfl(alpha, g * 4 + 2);
        float a3_ = __shfl(alpha, g * 4 + 3);
        #pragma unroll
        for (int dt = 0; dt < 4; ++dt) {
            acc_o[dt][0] *= a0_; acc_o[dt][1] *= a1_;
            acc_o[dt][2] *= a2_; acc_o[dt][3] *= a3_;
        }

        // PV: A = P rows (own q-strip), B = Vt rows (d)
        short8v pf0 = *(const short8v*)&Ps[(16 * w + r) * 72 + g * 8];
        short8v pf1 = *(const short8v*)&Ps[(16 * w + r) * 72 + 32 + g * 8];
        #pragma unroll
        for (int dt = 0; dt < 4; ++dt) {
            short8v vf0 = *(const short8v*)&Vs[(16 * dt + r) * 72 + g * 8];
            short8v vf1 = *(const short8v*)&Vs[(16 * dt + r) * 72 + 32 + g * 8];
            acc_o[dt] = __builtin_amdgcn_mfma_f32_16x16x32_bf16(pf0, vf0, acc_o[dt], 0, 0, 0);
            acc_o[dt] = __builtin_amdgcn_mfma_f32_16x16x32_bf16(pf1, vf1, acc_o[dt], 0, 0, 0);
        }
    }

    float il0 = 1.f / __shfl(l_own, g * 4 + 0);
    float il1 = 1.f / __shfl(l_own, g * 4 + 1);
    float il2 = 1.f / __shfl(l_own, g * 4 + 2);
    float il3 = 1.f / __shfl(l_own, g * 4 + 3);
    #pragma unroll
    for (int dt = 0; dt < 4; ++dt) {
        O[(size_t)(q0 + 16 * w + g * 4 + 0) * o_rs + 16 * dt + r] = f2bf(acc_o[dt][0] * il0);
        O[(size_t)(q0 + 16 * w + g * 4 + 1) * o_rs + 16 * dt + r] = f2bf(acc_o[dt][1] * il1);
        O[(size_t)(q0 + 16 * w + g * 4 + 2) * o_rs + 16 * dt + r] = f2bf(acc_o[dt][2] * il2);
        O[(size_t)(q0 + 16 * w + g * 4 + 3) * o_rs + 16 * dt + r] = f2bf(acc_o[dt][3] * il3);
    }
}

// ---------------------------------------------------------------- layernorm D=512, fp32 in -> bf16 out
__global__ __launch_bounds__(64) void ln_k(const float* __restrict__ X, unsigned short* __restrict__ Y,
                                           const float* __restrict__ g, const float* __restrict__ bt)
{
    int row = blockIdx.x, lane = threadIdx.x;
    const float* x = X + (size_t)row * 512;
    int c0 = lane * 4, c1 = 256 + lane * 4;
    float4 a0 = *(const float4*)&x[c0];
    float4 a1 = *(const float4*)&x[c1];
    float s  = a0.x + a0.y + a0.z + a0.w + a1.x + a1.y + a1.z + a1.w;
    float ss = a0.x * a0.x + a0.y * a0.y + a0.z * a0.z + a0.w * a0.w
             + a1.x * a1.x + a1.y * a1.y + a1.z * a1.z + a1.w * a1.w;
    #pragma unroll
    for (int off = 1; off < 64; off <<= 1) { s += __shfl_xor(s, off); ss += __shfl_xor(ss, off); }
    float mean = s * (1.f / 512.f);
    float var  = ss * (1.f / 512.f) - mean * mean;
    float rs = rsqrtf(var + 1e-5f);
    float4 g0 = *(const float4*)&g[c0], g1 = *(const float4*)&g[c1];
    float4 b0 = *(const float4*)&bt[c0], b1 = *(const float4*)&bt[c1];
    unsigned short* y = Y + (size_t)row * 512;
    ushort4 o0, o1;
    o0.x = f2bf((a0.x - mean) * rs * g0.x + b0.x);  o0.y = f2bf((a0.y - mean) * rs * g0.y + b0.y);
    o0.z = f2bf((a0.z - mean) * rs * g0.z + b0.z);  o0.w = f2bf((a0.w - mean) * rs * g0.w + b0.w);
    o1.x = f2bf((a1.x - mean) * rs * g1.x + b1.x);  o1.y = f2bf((a1.y - mean) * rs * g1.y + b1.y);
    o1.z = f2bf((a1.z - mean) * rs * g1.z + b1.z);  o1.w = f2bf((a1.w - mean) * rs * g1.w + b1.w);
    *(ushort4*)&y[c0] = o0;
    *(ushort4*)&y[c1] = o1;
}

// ---------------------------------------------------------------- gather gene embeddings -> bf16
__global__ __launch_bounds__(128) void gather_k(const float* __restrict__ ge, const int* __restrict__ ids,
                                                unsigned short* __restrict__ out)
{
    int gi = blockIdx.x, t = threadIdx.x;
    int id = ids[gi];
    float4 v = *(const float4*)&ge[(size_t)id * 512 + t * 4];
    ushort4 o;
    o.x = f2bf(v.x); o.y = f2bf(v.y); o.z = f2bf(v.z); o.w = f2bf(v.w);
    *(ushort4*)&out[(size_t)gi * 512 + t * 4] = o;
}

// ---------------------------------------------------------------- fused readout: pred = LN(z)*g+b . ro_w + ro_b
__global__ __launch_bounds__(64) void readout_k(const float* __restrict__ Z,
                                                const float* __restrict__ g, const float* __restrict__ bt,
                                                const float* __restrict__ rw, const float* __restrict__ rb,
                                                float* __restrict__ pred)
{
    int row = blockIdx.x, lane = threadIdx.x;
    const float* zr = Z + (size_t)row * 512;
    int c0 = lane * 4, c1 = 256 + lane * 4;
    float4 a0 = *(const float4*)&zr[c0];
    float4 a1 = *(const float4*)&zr[c1];
    float s  = a0.x + a0.y + a0.z + a0.w + a1.x + a1.y + a1.z + a1.w;
    float ss = a0.x * a0.x + a0.y * a0.y + a0.z * a0.z + a0.w * a0.w
             + a1.x * a1.x + a1.y * a1.y + a1.z * a1.z + a1.w * a1.w;
    #pragma unroll
    for (int off = 1; off < 64; off <<= 1) { s += __shfl_xor(s, off); ss += __shfl_xor(ss, off); }
    float mean = s * (1.f / 512.f);
    float var  = ss * (1.f / 512.f) - mean * mean;
    float rs = rsqrtf(var + 1e-5f);
    float4 g0 = *(const float4*)&g[c0], g1 = *(const float4*)&g[c1];
    float4 b0 = *(const float4*)&bt[c0], b1 = *(const float4*)&bt[c1];
    float4 w0 = *(const float4*)&rw[c0], w1 = *(const float4*)&rw[c1];
    float acc = 0.f;
    acc += ((a0.x - mean) * rs * g0.x + b0.x) * w0.x;
    acc += ((a0.y - mean) * rs * g0.y + b0.y) * w0.y;
    acc += ((a0.z - mean) * rs * g0.z + b0.z) * w0.z;
    acc += ((a0.w - mean) * rs * g0.w + b0.w) * w0.w;
    acc += ((a1.x - mean) * rs * g1.x + b1.x) * w1.x;
    acc += ((a1.y - mean) * rs * g1.y + b1.y) * w1.y;
    acc += ((a1.z - mean) * rs * g1.z + b1.z) * w1.z;
    acc += ((a1.w - mean) * rs * g1.w + b1.w) * w1.w;
    #pragma unroll
    for (int off = 1; off < 64; off <<= 1) acc += __shfl_xor(acc, off);
    if (lane == 0) pred[row] = acc + rb[0];
}

// ---------------------------------------------------------------- launch
extern "C" void kernel_launch(void* const* d_in, const int* in_sizes, int n_in,
                              void* d_out, int out_size, void* d_ws, size_t ws_size,
                              hipStream_t stream)
{
    (void)in_sizes; (void)n_in; (void)out_size; (void)ws_size;
    const float* windows    = (const float*)d_in[0];
    const int*   gene_ids   = (const int*)  d_in[1];
    const float* W_window   = (const float*)d_in[2];
    const float* enc_qkv_w  = (const float*)d_in[3];
    const float* enc_qkv_b  = (const float*)d_in[4];
    const float* enc_out_w  = (const float*)d_in[5];
    const float* enc_out_b  = (const float*)d_in[6];
    const float* enc_ln1_g  = (const float*)d_in[7];
    const float* enc_ln1_b  = (const float*)d_in[8];
    const float* enc_ln2_g  = (const float*)d_in[9];
    const float* enc_ln2_b  = (const float*)d_in[10];
    const float* enc_ff1_w  = (const float*)d_in[11];
    const float* enc_ff1_b  = (const float*)d_in[12];
    const float* enc_ff2_w  = (const float*)d_in[13];
    const float* enc_ff2_b  = (const float*)d_in[14];
    const float* gene_embed = (const float*)d_in[15];
    const float* ca_qkv_w   = (const float*)d_in[16];
    const float* ca_qkv_b   = (const float*)d_in[17];
    const float* ca_out_w   = (const float*)d_in[18];
    const float* ca_out_b   = (const float*)d_in[19];
    const float* ro_ln_g    = (const float*)d_in[20];
    const float* ro_ln_b    = (const float*)d_in[21];
    const float* ro_w       = (const float*)d_in[22];
    const float* ro_b       = (const float*)d_in[23];

    float* pred = (float*)d_out;
    float* z    = pred + (size_t)8 * 2048;

    // workspace carve-up (~79 MB)
    char* wp = (char*)d_ws;
    float* x = (float*)wp;                       wp += (size_t)4096 * 512 * 4;   // 8 MB
    unsigned short* x16   = (unsigned short*)wp; wp += (size_t)4096 * 512 * 2;   // 4 MB
    unsigned short* h16   = (unsigned short*)wp; wp += (size_t)4096 * 512 * 2;   // 4 MB
    unsigned short* qkv16 = (unsigned short*)wp; wp += (size_t)4096 * 1536 * 2;  // 12 MB
    unsigned short* ao16  = (unsigned short*)wp; wp += (size_t)4096 * 512 * 2;   // 4 MB
    unsigned short* big16 = (unsigned short*)wp; wp += (size_t)16384 * 512 * 2;  // 16 MB
    unsigned short* vt16  = (unsigned short*)wp; wp += (size_t)512 * 4096 * 2;   // 4 MB
    unsigned short* wW16     = (unsigned short*)wp; wp += (size_t)512 * 1024 * 2;
    unsigned short* wqkv16   = (unsigned short*)wp; wp += (size_t)4 * 1536 * 512 * 2;
    unsigned short* wout16   = (unsigned short*)wp; wp += (size_t)4 * 512 * 512 * 2;
    unsigned short* wff116   = (unsigned short*)wp; wp += (size_t)4 * 2048 * 512 * 2;
    unsigned short* wff216   = (unsigned short*)wp; wp += (size_t)4 * 512 * 2048 * 2;
    unsigned short* wcaqkv16 = (unsigned short*)wp; wp += (size_t)1536 * 512 * 2;
    unsigned short* wcaout16 = (unsigned short*)wp; wp += (size_t)512 * 512 * 2;
    // aliases (lifetimes disjoint)
    unsigned short* pw16  = big16;                          // 4096x1024
    unsigned short* ff116 = big16;                          // 4096x2048
    unsigned short* oc16  = big16;                          // 16384x512
    unsigned short* ge16  = qkv16;                          // 2048x512
    unsigned short* qg16  = qkv16 + (size_t)2048 * 512;     // 2048x512
    unsigned short* kc16  = qkv16 + (size_t)2 * 2048 * 512; // 4096x512

    auto cvt = [&](const float* s, unsigned short* d, int n) {
        cvt_k<<<(n / 4 + 255) / 256, 256, 0, stream>>>(s, d, n / 4);
    };
    cvt(W_window,  wW16,     512 * 1024);
    cvt(enc_qkv_w, wqkv16,   4 * 1536 * 512);
    cvt(enc_out_w, wout16,   4 * 512 * 512);
    cvt(enc_ff1_w, wff116,   4 * 2048 * 512);
    cvt(enc_ff2_w, wff216,   4 * 512 * 2048);
    cvt(ca_qkv_w,  wcaqkv16, 1536 * 512);
    cvt(ca_out_w,  wcaout16, 512 * 512);

    // 1) pool + window projection + posenc -> x (fp32)
    pool_windows_k<<<4096, 256, 0, stream>>>(windows, pw16);
    gemm_bf16_k<false, false, false, false, true, true, false><<<dim3(4, 32), 256, 0, stream>>>(
        pw16, wW16, nullptr, nullptr, x, nullptr, 4096, 512, 1024);

    // 2) encoder layers
    for (int l = 0; l < 4; ++l) {
        const unsigned short* wl = wqkv16 + (size_t)l * 1536 * 512;
        ln_k<<<4096, 64, 0, stream>>>(x, h16, enc_ln1_g + l * 512, enc_ln1_b + l * 512);
        // QK projection (cols 0..1023 of qkv)
        gemm_bf16_k<true, false, false, false, false, false, true><<<dim3(8, 32), 256, 0, stream>>>(
            h16, wl, enc_qkv_b + l * 1536, nullptr, nullptr, qkv16, 4096, 1024, 512);
        // V^T = Wv * h^T  (bias per row)
        gemm_bf16_k<true, true, false, false, false, false, true><<<dim3(32, 4), 256, 0, stream>>>(
            wl + (size_t)1024 * 512, h16, enc_qkv_b + l * 1536 + 1024, nullptr,
            nullptr, vt16, 512, 4096, 512);
        flashb_k<<<dim3(8, 8, 8), 256, 0, stream>>>(
            qkv16, (long long)512 * 1024, 1024,
            qkv16 + 512, (long long)512 * 1024, 1024,
            vt16, (long long)64 * 4096, 512LL, 4096,
            ao16, (long long)512 * 512, 512, 512);
        gemm_bf16_k<true, false, true, false, false, true, false><<<dim3(4, 32), 256, 0, stream>>>(
            ao16, wout16 + (size_t)l * 512 * 512, enc_out_b + l * 512, x, x, nullptr, 4096, 512, 512);
        ln_k<<<4096, 64, 0, stream>>>(x, h16, enc_ln2_g + l * 512, enc_ln2_b + l * 512);
        gemm_bf16_k<true, false, false, true, false, false, true><<<dim3(16, 32), 256, 0, stream>>>(
            h16, wff116 + (size_t)l * 2048 * 512, enc_ff1_b + l * 2048, nullptr,
            nullptr, ff116, 4096, 2048, 512);
        if (l == 3)
            gemm_bf16_k<true, false, true, false, false, true, true><<<dim3(4, 32), 256, 0, stream>>>(
                ff116, wff216 + (size_t)l * 512 * 2048, enc_ff2_b + l * 512, x, x, x16, 4096, 512, 2048);
        else
            gemm_bf16_k<true, false, true, false, false, true, false><<<dim3(4, 32), 256, 0, stream>>>(
                ff116, wff216 + (size_t)l * 512 * 2048, enc_ff2_b + l * 512, x, x, nullptr, 4096, 512, 2048);
    }

    // 3) cross-attention
    gather_k<<<2048, 128, 0, stream>>>(gene_embed, gene_ids, ge16);
    gemm_bf16_k<true, false, false, false, false, false, true><<<dim3(4, 16), 256, 0, stream>>>(
        ge16, wcaqkv16, ca_qkv_b, nullptr, nullptr, qg16, 2048, 512, 512);
    gemm_bf16_k<true, false, false, false, false, false, true><<<dim3(4, 32), 256, 0, stream>>>(
        x16, wcaqkv16 + (size_t)512 * 512, ca_qkv_b + 512, nullptr, nullptr, kc16, 4096, 512, 512);
    gemm_bf16_k<true, true, false, false, false, false, true><<<dim3(32, 4), 256, 0, stream>>>(
        wcaqkv16 + (size_t)1024 * 512, x16, ca_qkv_b + 1024, nullptr, nullptr, vt16, 512, 4096, 512);
    flashb_k<<<dim3(32, 8, 8), 256, 0, stream>>>(
        qg16, 0LL, 512,
        kc16, (long long)512 * 512, 512,
        vt16, (long long)64 * 4096, 512LL, 4096,
        oc16, (long long)2048 * 512, 512, 512);
    gemm_bf16_k<true, false, false, false, false, true, false><<<dim3(4, 128), 256, 0, stream>>>(
        oc16, wcaout16, ca_out_b, nullptr, z, nullptr, 16384, 512, 512);

    // 4) readout
    readout_k<<<16384, 64, 0, stream>>>(z, ro_ln_g, ro_ln_b, ro_w, ro_b, pred);
}

// Round 4
// 616.470 us; speedup vs baseline: 3.9277x; 1.1592x over previous
//
#include <hip/hip_runtime.h>
#include <math.h>

// MultiomicTransformer on MI355X — Round 4: flash VALU diet + BM=64 GEMM tiles.
// B=8 W=2048 WIN=1024 D=512 NH=8 HD=64 DFF=2048 L=4 KS=4 G=2048 S=512

typedef __attribute__((ext_vector_type(8))) short short8v;
typedef __attribute__((ext_vector_type(4))) float float4v;
typedef const __attribute__((address_space(1))) void* gas_t;
typedef __attribute__((address_space(3))) void* las_t;

__device__ inline unsigned short f2bf(float f) {
    unsigned int u = __builtin_bit_cast(unsigned int, f);
    return (unsigned short)((u + 0x7fffu + ((u >> 16) & 1u)) >> 16);   // RNE
}

__device__ inline unsigned cvt_pk_bf16(float lo, float hi) {          // [bf16(lo) | bf16(hi)<<16]
    unsigned r;
    asm("v_cvt_pk_bf16_f32 %0, %1, %2" : "=v"(r) : "v"(lo), "v"(hi));
    return r;
}

// ---------------------------------------------------------------- fp32 -> bf16 bulk convert
__global__ __launch_bounds__(256) void cvt_k(const float* __restrict__ src,
                                             unsigned short* __restrict__ dst, int n4)
{
    int i = blockIdx.x * 256 + threadIdx.x;
    if (i >= n4) return;
    float4 v = ((const float4*)src)[i];
    ushort4 o;
    o.x = f2bf(v.x); o.y = f2bf(v.y); o.z = f2bf(v.z); o.w = f2bf(v.w);
    ((ushort4*)dst)[i] = o;
}

// ---------------------------------------------------------------- pool mean-4 (commutes with win-proj), bf16 out
__global__ __launch_bounds__(256) void pool_windows_k(const float* __restrict__ win,
                                                      unsigned short* __restrict__ pw)
{
    int idx = blockIdx.x * 256 + threadIdx.x;
    int n = idx >> 8, c4 = (idx & 255) << 2;
    const float* base = win + (size_t)n * 4096 + c4;
    float4 a = *(const float4*)(base);
    float4 b2 = *(const float4*)(base + 1024);
    float4 c = *(const float4*)(base + 2048);
    float4 d = *(const float4*)(base + 3072);
    ushort4 r;
    r.x = f2bf((a.x + b2.x + c.x + d.x) * 0.25f);
    r.y = f2bf((a.y + b2.y + c.y + d.y) * 0.25f);
    r.z = f2bf((a.z + b2.z + c.z + d.z) * 0.25f);
    r.w = f2bf((a.w + b2.w + c.w + d.w) * 0.25f);
    ((ushort4*)pw)[idx] = r;
}

// ---------------------------------------------------------------- bf16 MFMA GEMM
// C[M,N] = A[M,K] * Bw[N,K]^T. Tile BM x 128 (BM = 128: 2x2 waves of 64x64;
// BM = 64: 1x4 waves of 64x32 — doubles grid for small-N shapes). K-step 32.
template<int BM, bool BIAS, bool BROW, bool RES, bool RELU, bool POSENC, bool O32, bool O16>
__global__ __launch_bounds__(256) void gemm_bf16_k(
    const unsigned short* __restrict__ A, const unsigned short* __restrict__ Bw,
    const float* __restrict__ bias, const float* __restrict__ Res,
    float* __restrict__ C32, unsigned short* __restrict__ C16,
    int M, int N, int K)
{
    constexpr int WC   = (BM == 128) ? 2 : 4;   // wave cols
    constexpr int NSTEP = 128 / WC;             // wave col span: 64 or 32
    constexpr int MFR  = 4;                     // 16-row frags per wave
    constexpr int NFR  = NSTEP / 16;            // 4 or 2
    __shared__ __align__(16) unsigned short As[BM * 32];
    __shared__ __align__(16) unsigned short Bs[128 * 32];
    const int tid = threadIdx.x;
    const int lane = tid & 63;
    const int n0 = blockIdx.x * 128, m0 = blockIdx.y * BM;
    const int wr = (BM == 128) ? (tid >> 7) : 0;
    const int wc = (tid >> 6) & (WC - 1);
    const unsigned short* gA0 = A + (size_t)(m0 + (tid >> 2)) * K + (tid & 3) * 8;
    const unsigned short* gA1 = A + (size_t)(m0 + (tid >> 2) + 64) * K + (tid & 3) * 8;
    const unsigned short* gB0 = Bw + (size_t)(n0 + (tid >> 2)) * K + (tid & 3) * 8;
    const unsigned short* gB1 = Bw + (size_t)(n0 + (tid >> 2) + 64) * K + (tid & 3) * 8;
    const int r = lane & 15, g = lane >> 4;
    const int aoff = (64 * wr + r) * 32 + g * 8;
    const int boff = (NSTEP * wc + r) * 32 + g * 8;

    float4v acc[MFR][NFR];
    float4v z4 = {0.f, 0.f, 0.f, 0.f};
    #pragma unroll
    for (int i = 0; i < MFR; ++i)
        #pragma unroll
        for (int j = 0; j < NFR; ++j) acc[i][j] = z4;

    for (int k0 = 0; k0 < K; k0 += 32) {
        __builtin_amdgcn_global_load_lds((gas_t)(gA0 + k0), (las_t)(&As[tid * 8]), 16, 0, 0);
        if constexpr (BM == 128)
            __builtin_amdgcn_global_load_lds((gas_t)(gA1 + k0), (las_t)(&As[(tid + 256) * 8]), 16, 0, 0);
        __builtin_amdgcn_global_load_lds((gas_t)(gB0 + k0), (las_t)(&Bs[tid * 8]), 16, 0, 0);
        __builtin_amdgcn_global_load_lds((gas_t)(gB1 + k0), (las_t)(&Bs[(tid + 256) * 8]), 16, 0, 0);
        __syncthreads();
        short8v a[MFR], b[NFR];
        #pragma unroll
        for (int mi = 0; mi < MFR; ++mi) a[mi] = *(const short8v*)&As[aoff + mi * (16 * 32)];
        #pragma unroll
        for (int ni = 0; ni < NFR; ++ni) b[ni] = *(const short8v*)&Bs[boff + ni * (16 * 32)];
        #pragma unroll
        for (int mi = 0; mi < MFR; ++mi)
            #pragma unroll
            for (int ni = 0; ni < NFR; ++ni)
                acc[mi][ni] = __builtin_amdgcn_mfma_f32_16x16x32_bf16(a[mi], b[ni], acc[mi][ni], 0, 0, 0);
        __syncthreads();
    }

    #pragma unroll
    for (int mi = 0; mi < MFR; ++mi) {
        #pragma unroll
        for (int ni = 0; ni < NFR; ++ni) {
            const int row0 = m0 + 64 * wr + 16 * mi + g * 4;
            const int col  = n0 + NSTEP * wc + 16 * ni + r;
            float bv = (BIAS && !BROW) ? bias[col] : 0.f;
            float fr = 0.f;
            if (POSENC) fr = __expf((float)(col & ~1) * -0.01798894600f);
            #pragma unroll
            for (int q = 0; q < 4; ++q) {
                const int row = row0 + q;
                float v = acc[mi][ni][q] + bv;
                if (BIAS && BROW) v += bias[row];
                if (POSENC) {
                    float ang = (float)(row & 511) * fr;
                    v += (col & 1) ? __cosf(ang) : __sinf(ang);
                }
                if (RES) v += Res[(size_t)row * N + col];
                if (RELU) v = fmaxf(v, 0.f);
                if (O32) C32[(size_t)row * N + col] = v;
                if (O16) C16[(size_t)row * N + col] = f2bf(v);
            }
        }
    }
}

// ---------------------------------------------------------------- flash attention, bf16, hd=64
// 4 waves x 16 q-rows; kv chunks of 64; swapped QK^T (P lane-local in kv),
// V pre-transposed in global (Vt[dcol][token]); Q frags direct from global.
// exp2-form online softmax with defer-max (THR=64 raw = 8 exp-units).
__global__ __launch_bounds__(256) void flashb_k(
    const unsigned short* __restrict__ Qp, long long q_bs, int q_rs,
    const unsigned short* __restrict__ Kp, long long k_bs, int k_rs,
    const unsigned short* __restrict__ Vtp, long long v_hs, long long v_bs, int v_rs,
    unsigned short* __restrict__ Op, long long o_bs, int o_rs, int skv)
{
    constexpr float C1 = 0.18033688011112042f;   // 0.125 * log2(e)
    __shared__ __align__(16) unsigned short Ks[64 * 72];
    __shared__ __align__(16) unsigned short Vs[64 * 72];
    __shared__ __align__(16) unsigned short Ps[64 * 72];
    const int qt = blockIdx.x, h = blockIdx.y, b = blockIdx.z;
    const unsigned short* Q  = Qp  + (size_t)b * q_bs + (size_t)h * 64;
    const unsigned short* K  = Kp  + (size_t)b * k_bs + (size_t)h * 64;
    const unsigned short* Vt = Vtp + (size_t)h * v_hs + (size_t)b * v_bs;
    unsigned short* O = Op + (size_t)b * o_bs + (size_t)h * 64;
    const int q0 = qt * 64;
    const int tid = threadIdx.x, lane = tid & 63, w = tid >> 6;
    const int r = lane & 15, g = lane >> 4;

    const unsigned short* qrow = Q + (size_t)(q0 + 16 * w + r) * q_rs + g * 8;
    short8v qf0 = *(const short8v*)(qrow);
    short8v qf1 = *(const short8v*)(qrow + 32);

    const int sr0 = tid >> 3, sr1 = sr0 + 32, sc0 = (tid & 7) * 8;
    const unsigned short* Krow0 = K + (size_t)sr0 * k_rs + sc0;
    const unsigned short* Krow1 = K + (size_t)sr1 * k_rs + sc0;
    const unsigned short* Vrow0 = Vt + (size_t)sr0 * v_rs + sc0;
    const unsigned short* Vrow1 = Vt + (size_t)sr1 * v_rs + sc0;

    uint4 pk0 = *(const uint4*)(Krow0);
    uint4 pk1 = *(const uint4*)(Krow1);
    uint4 pv0 = *(const uint4*)(Vrow0);
    uint4 pv1 = *(const uint4*)(Vrow1);

    float4v acc_o[4];
    float4v z4 = {0.f, 0.f, 0.f, 0.f};
    #pragma unroll
    for (int dt = 0; dt < 4; ++dt) acc_o[dt] = z4;
    float m_own = -INFINITY, l_own = 0.f;

    for (int kv0 = 0; kv0 < skv; kv0 += 64) {
        __syncthreads();
        *(uint4*)&Ks[sr0 * 72 + sc0] = pk0;
        *(uint4*)&Ks[sr1 * 72 + sc0] = pk1;
        *(uint4*)&Vs[sr0 * 72 + sc0] = pv0;
        *(uint4*)&Vs[sr1 * 72 + sc0] = pv1;
        __syncthreads();
        const int kvn = kv0 + 64;
        if (kvn < skv) {
            pk0 = *(const uint4*)(Krow0 + (size_t)kvn * k_rs);
            pk1 = *(const uint4*)(Krow1 + (size_t)kvn * k_rs);
            pv0 = *(const uint4*)(Vrow0 + kvn);
            pv1 = *(const uint4*)(Vrow1 + kvn);
        }

        // swapped QK^T: lane holds S[q=r][kv=16t+g*4+reg]
        float4v accs[4];
        #pragma unroll
        for (int t = 0; t < 4; ++t) {
            accs[t] = z4;
            short8v kf0 = *(const short8v*)&Ks[(16 * t + r) * 72 + g * 8];
            short8v kf1 = *(const short8v*)&Ks[(16 * t + r) * 72 + 32 + g * 8];
            accs[t] = __builtin_amdgcn_mfma_f32_16x16x32_bf16(kf0, qf0, accs[t], 0, 0, 0);
            accs[t] = __builtin_amdgcn_mfma_f32_16x16x32_bf16(kf1, qf1, accs[t], 0, 0, 0);
        }

        // chunk max across lanes sharing l&15
        float sm = accs[0][0];
        #pragma unroll
        for (int t = 0; t < 4; ++t)
            #pragma unroll
            for (int j = 0; j < 4; ++j) sm = fmaxf(sm, accs[t][j]);
        sm = fmaxf(sm, __shfl_xor(sm, 16));
        sm = fmaxf(sm, __shfl_xor(sm, 32));

        // defer-max: only pay the rescale path when max grew by > 64 raw (8 exp-units)
        if (__any(sm > m_own + 64.f)) {
            float mn = fmaxf(m_own, sm);
            float alpha = __builtin_amdgcn_exp2f((m_own - mn) * C1);   // first chunk: 0
            m_own = mn;
            float a0_ = __shfl(alpha, g * 4 + 0);
            float a1_ = __shfl(alpha, g * 4 + 1);
            float a2_ = __shfl(alpha, g * 4 + 2);
            float a3_ = __shfl(alpha, g * 4 + 3);
            #pragma unroll
            for (int dt = 0; dt < 4; ++dt) {
                acc_o[dt][0] *= a0_; acc_o[dt][1] *= a1_;
                acc_o[dt][2] *= a2_; acc_o[dt][3] *= a3_;
            }
            l_own *= alpha;
        }

        const float m2 = m_own * C1;
        float p[4][4];
        float rsum = 0.f;
        #pragma unroll
        for (int t = 0; t < 4; ++t)
            #pragma unroll
            for (int j = 0; j < 4; ++j) {
                float pv = __builtin_amdgcn_exp2f(__builtin_fmaf(accs[t][j], C1, -m2));
                p[t][j] = pv; rsum += pv;
            }
        rsum += __shfl_xor(rsum, 16);
        rsum += __shfl_xor(rsum, 32);
        l_own += rsum;

        // P write: hw packed cvt, 2x ds_write_b64-equiv per t
        #pragma unroll
        for (int t = 0; t < 4; ++t) {
            uint2 uu;
            uu.x = cvt_pk_bf16(p[t][0], p[t][1]);
            uu.y = cvt_pk_bf16(p[t][2], p[t][3]);
            *(uint2*)&Ps[(16 * w + r) * 72 + 16 * t + g * 4] = uu;
        }

        // PV (P rows are wave-private: no barrier needed)
        short8v pf0 = *(const short8v*)&Ps[(16 * w + r) * 72 + g * 8];
        short8v pf1 = *(const short8v*)&Ps[(16 * w + r) * 72 + 32 + g * 8];
        #pragma unroll
        for (int dt = 0; dt < 4; ++dt) {
            short8v vf0 = *(const short8v*)&Vs[(16 * dt + r) * 72 + g * 8];
            short8v vf1 = *(const short8v*)&Vs[(16 * dt + r) * 72 + 32 + g * 8];
            acc_o[dt] = __builtin_amdgcn_mfma_f32_16x16x32_bf16(pf0, vf0, acc_o[dt], 0, 0, 0);
            acc_o[dt] = __builtin_amdgcn_mfma_f32_16x16x32_bf16(pf1, vf1, acc_o[dt], 0, 0, 0);
        }
    }

    float il0 = 1.f / __shfl(l_own, g * 4 + 0);
    float il1 = 1.f / __shfl(l_own, g * 4 + 1);
    float il2 = 1.f / __shfl(l_own, g * 4 + 2);
    float il3 = 1.f / __shfl(l_own, g * 4 + 3);
    #pragma unroll
    for (int dt = 0; dt < 4; ++dt) {
        O[(size_t)(q0 + 16 * w + g * 4 + 0) * o_rs + 16 * dt + r] = f2bf(acc_o[dt][0] * il0);
        O[(size_t)(q0 + 16 * w + g * 4 + 1) * o_rs + 16 * dt + r] = f2bf(acc_o[dt][1] * il1);
        O[(size_t)(q0 + 16 * w + g * 4 + 2) * o_rs + 16 * dt + r] = f2bf(acc_o[dt][2] * il2);
        O[(size_t)(q0 + 16 * w + g * 4 + 3) * o_rs + 16 * dt + r] = f2bf(acc_o[dt][3] * il3);
    }
}

// ---------------------------------------------------------------- layernorm D=512, fp32 in -> bf16 out
__global__ __launch_bounds__(64) void ln_k(const float* __restrict__ X, unsigned short* __restrict__ Y,
                                           const float* __restrict__ g, const float* __restrict__ bt)
{
    int row = blockIdx.x, lane = threadIdx.x;
    const float* x = X + (size_t)row * 512;
    int c0 = lane * 4, c1 = 256 + lane * 4;
    float4 a0 = *(const float4*)&x[c0];
    float4 a1 = *(const float4*)&x[c1];
    float s  = a0.x + a0.y + a0.z + a0.w + a1.x + a1.y + a1.z + a1.w;
    float ss = a0.x * a0.x + a0.y * a0.y + a0.z * a0.z + a0.w * a0.w
             + a1.x * a1.x + a1.y * a1.y + a1.z * a1.z + a1.w * a1.w;
    #pragma unroll
    for (int off = 1; off < 64; off <<= 1) { s += __shfl_xor(s, off); ss += __shfl_xor(ss, off); }
    float mean = s * (1.f / 512.f);
    float var  = ss * (1.f / 512.f) - mean * mean;
    float rs = rsqrtf(var + 1e-5f);
    float4 g0 = *(const float4*)&g[c0], g1 = *(const float4*)&g[c1];
    float4 b0 = *(const float4*)&bt[c0], b1 = *(const float4*)&bt[c1];
    unsigned short* y = Y + (size_t)row * 512;
    ushort4 o0, o1;
    o0.x = f2bf((a0.x - mean) * rs * g0.x + b0.x);  o0.y = f2bf((a0.y - mean) * rs * g0.y + b0.y);
    o0.z = f2bf((a0.z - mean) * rs * g0.z + b0.z);  o0.w = f2bf((a0.w - mean) * rs * g0.w + b0.w);
    o1.x = f2bf((a1.x - mean) * rs * g1.x + b1.x);  o1.y = f2bf((a1.y - mean) * rs * g1.y + b1.y);
    o1.z = f2bf((a1.z - mean) * rs * g1.z + b1.z);  o1.w = f2bf((a1.w - mean) * rs * g1.w + b1.w);
    *(ushort4*)&y[c0] = o0;
    *(ushort4*)&y[c1] = o1;
}

// ---------------------------------------------------------------- gather gene embeddings -> bf16
__global__ __launch_bounds__(128) void gather_k(const float* __restrict__ ge, const int* __restrict__ ids,
                                                unsigned short* __restrict__ out)
{
    int gi = blockIdx.x, t = threadIdx.x;
    int id = ids[gi];
    float4 v = *(const float4*)&ge[(size_t)id * 512 + t * 4];
    ushort4 o;
    o.x = f2bf(v.x); o.y = f2bf(v.y); o.z = f2bf(v.z); o.w = f2bf(v.w);
    *(ushort4*)&out[(size_t)gi * 512 + t * 4] = o;
}

// ---------------------------------------------------------------- fused readout: pred = LN(z)*g+b . ro_w + ro_b
__global__ __launch_bounds__(64) void readout_k(const float* __restrict__ Z,
                                                const float* __restrict__ g, const float* __restrict__ bt,
                                                const float* __restrict__ rw, const float* __restrict__ rb,
                                                float* __restrict__ pred)
{
    int row = blockIdx.x, lane = threadIdx.x;
    const float* zr = Z + (size_t)row * 512;
    int c0 = lane * 4, c1 = 256 + lane * 4;
    float4 a0 = *(const float4*)&zr[c0];
    float4 a1 = *(const float4*)&zr[c1];
    float s  = a0.x + a0.y + a0.z + a0.w + a1.x + a1.y + a1.z + a1.w;
    float ss = a0.x * a0.x + a0.y * a0.y + a0.z * a0.z + a0.w * a0.w
             + a1.x * a1.x + a1.y * a1.y + a1.z * a1.z + a1.w * a1.w;
    #pragma unroll
    for (int off = 1; off < 64; off <<= 1) { s += __shfl_xor(s, off); ss += __shfl_xor(ss, off); }
    float mean = s * (1.f / 512.f);
    float var  = ss * (1.f / 512.f) - mean * mean;
    float rs = rsqrtf(var + 1e-5f);
    float4 g0 = *(const float4*)&g[c0], g1 = *(const float4*)&g[c1];
    float4 b0 = *(const float4*)&bt[c0], b1 = *(const float4*)&bt[c1];
    float4 w0 = *(const float4*)&rw[c0], w1 = *(const float4*)&rw[c1];
    float acc = 0.f;
    acc += ((a0.x - mean) * rs * g0.x + b0.x) * w0.x;
    acc += ((a0.y - mean) * rs * g0.y + b0.y) * w0.y;
    acc += ((a0.z - mean) * rs * g0.z + b0.z) * w0.z;
    acc += ((a0.w - mean) * rs * g0.w + b0.w) * w0.w;
    acc += ((a1.x - mean) * rs * g1.x + b1.x) * w1.x;
    acc += ((a1.y - mean) * rs * g1.y + b1.y) * w1.y;
    acc += ((a1.z - mean) * rs * g1.z + b1.z) * w1.z;
    acc += ((a1.w - mean) * rs * g1.w + b1.w) * w1.w;
    #pragma unroll
    for (int off = 1; off < 64; off <<= 1) acc += __shfl_xor(acc, off);
    if (lane == 0) pred[row] = acc + rb[0];
}

// ---------------------------------------------------------------- launch
extern "C" void kernel_launch(void* const* d_in, const int* in_sizes, int n_in,
                              void* d_out, int out_size, void* d_ws, size_t ws_size,
                              hipStream_t stream)
{
    (void)in_sizes; (void)n_in; (void)out_size; (void)ws_size;
    const float* windows    = (const float*)d_in[0];
    const int*   gene_ids   = (const int*)  d_in[1];
    const float* W_window   = (const float*)d_in[2];
    const float* enc_qkv_w  = (const float*)d_in[3];
    const float* enc_qkv_b  = (const float*)d_in[4];
    const float* enc_out_w  = (const float*)d_in[5];
    const float* enc_out_b  = (const float*)d_in[6];
    const float* enc_ln1_g  = (const float*)d_in[7];
    const float* enc_ln1_b  = (const float*)d_in[8];
    const float* enc_ln2_g  = (const float*)d_in[9];
    const float* enc_ln2_b  = (const float*)d_in[10];
    const float* enc_ff1_w  = (const float*)d_in[11];
    const float* enc_ff1_b  = (const float*)d_in[12];
    const float* enc_ff2_w  = (const float*)d_in[13];
    const float* enc_ff2_b  = (const float*)d_in[14];
    const float* gene_embed = (const float*)d_in[15];
    const float* ca_qkv_w   = (const float*)d_in[16];
    const float* ca_qkv_b   = (const float*)d_in[17];
    const float* ca_out_w   = (const float*)d_in[18];
    const float* ca_out_b   = (const float*)d_in[19];
    const float* ro_ln_g    = (const float*)d_in[20];
    const float* ro_ln_b    = (const float*)d_in[21];
    const float* ro_w       = (const float*)d_in[22];
    const float* ro_b       = (const float*)d_in[23];

    float* pred = (float*)d_out;
    float* z    = pred + (size_t)8 * 2048;

    // workspace carve-up (~79 MB)
    char* wp = (char*)d_ws;
    float* x = (float*)wp;                       wp += (size_t)4096 * 512 * 4;   // 8 MB
    unsigned short* x16   = (unsigned short*)wp; wp += (size_t)4096 * 512 * 2;   // 4 MB
    unsigned short* h16   = (unsigned short*)wp; wp += (size_t)4096 * 512 * 2;   // 4 MB
    unsigned short* qkv16 = (unsigned short*)wp; wp += (size_t)4096 * 1536 * 2;  // 12 MB
    unsigned short* ao16  = (unsigned short*)wp; wp += (size_t)4096 * 512 * 2;   // 4 MB
    unsigned short* big16 = (unsigned short*)wp; wp += (size_t)16384 * 512 * 2;  // 16 MB
    unsigned short* vt16  = (unsigned short*)wp; wp += (size_t)512 * 4096 * 2;   // 4 MB
    unsigned short* wW16     = (unsigned short*)wp; wp += (size_t)512 * 1024 * 2;
    unsigned short* wqkv16   = (unsigned short*)wp; wp += (size_t)4 * 1536 * 512 * 2;
    unsigned short* wout16   = (unsigned short*)wp; wp += (size_t)4 * 512 * 512 * 2;
    unsigned short* wff116   = (unsigned short*)wp; wp += (size_t)4 * 2048 * 512 * 2;
    unsigned short* wff216   = (unsigned short*)wp; wp += (size_t)4 * 512 * 2048 * 2;
    unsigned short* wcaqkv16 = (unsigned short*)wp; wp += (size_t)1536 * 512 * 2;
    unsigned short* wcaout16 = (unsigned short*)wp; wp += (size_t)512 * 512 * 2;
    // aliases (lifetimes disjoint)
    unsigned short* pw16  = big16;                          // 4096x1024
    unsigned short* ff116 = big16;                          // 4096x2048
    unsigned short* oc16  = big16;                          // 16384x512
    unsigned short* ge16  = qkv16;                          // 2048x512
    unsigned short* qg16  = qkv16 + (size_t)2048 * 512;     // 2048x512
    unsigned short* kc16  = qkv16 + (size_t)2 * 2048 * 512; // 4096x512

    auto cvt = [&](const float* s, unsigned short* d, int n) {
        cvt_k<<<(n / 4 + 255) / 256, 256, 0, stream>>>(s, d, n / 4);
    };
    cvt(W_window,  wW16,     512 * 1024);
    cvt(enc_qkv_w, wqkv16,   4 * 1536 * 512);
    cvt(enc_out_w, wout16,   4 * 512 * 512);
    cvt(enc_ff1_w, wff116,   4 * 2048 * 512);
    cvt(enc_ff2_w, wff216,   4 * 512 * 2048);
    cvt(ca_qkv_w,  wcaqkv16, 1536 * 512);
    cvt(ca_out_w,  wcaout16, 512 * 512);

    // 1) pool + window projection + posenc -> x (fp32)
    pool_windows_k<<<4096, 256, 0, stream>>>(windows, pw16);
    gemm_bf16_k<64, false, false, false, false, true, true, false><<<dim3(4, 64), 256, 0, stream>>>(
        pw16, wW16, nullptr, nullptr, x, nullptr, 4096, 512, 1024);

    // 2) encoder layers
    for (int l = 0; l < 4; ++l) {
        const unsigned short* wl = wqkv16 + (size_t)l * 1536 * 512;
        ln_k<<<4096, 64, 0, stream>>>(x, h16, enc_ln1_g + l * 512, enc_ln1_b + l * 512);
        // QK projection (cols 0..1023 of qkv)
        gemm_bf16_k<128, true, false, false, false, false, false, true><<<dim3(8, 32), 256, 0, stream>>>(
            h16, wl, enc_qkv_b + l * 1536, nullptr, nullptr, qkv16, 4096, 1024, 512);
        // V^T = Wv * h^T  (bias per row)
        gemm_bf16_k<64, true, true, false, false, false, false, true><<<dim3(32, 8), 256, 0, stream>>>(
            wl + (size_t)1024 * 512, h16, enc_qkv_b + l * 1536 + 1024, nullptr,
            nullptr, vt16, 512, 4096, 512);
        flashb_k<<<dim3(8, 8, 8), 256, 0, stream>>>(
            qkv16, (long long)512 * 1024, 1024,
            qkv16 + 512, (long long)512 * 1024, 1024,
            vt16, (long long)64 * 4096, 512LL, 4096,
            ao16, (long long)512 * 512, 512, 512);
        gemm_bf16_k<64, true, false, true, false, false, true, false><<<dim3(4, 64), 256, 0, stream>>>(
            ao16, wout16 + (size_t)l * 512 * 512, enc_out_b + l * 512, x, x, nullptr, 4096, 512, 512);
        ln_k<<<4096, 64, 0, stream>>>(x, h16, enc_ln2_g + l * 512, enc_ln2_b + l * 512);
        gemm_bf16_k<128, true, false, false, true, false, false, true><<<dim3(16, 32), 256, 0, stream>>>(
            h16, wff116 + (size_t)l * 2048 * 512, enc_ff1_b + l * 2048, nullptr,
            nullptr, ff116, 4096, 2048, 512);
        if (l == 3)
            gemm_bf16_k<64, true, false, true, false, false, true, true><<<dim3(4, 64), 256, 0, stream>>>(
                ff116, wff216 + (size_t)l * 512 * 2048, enc_ff2_b + l * 512, x, x, x16, 4096, 512, 2048);
        else
            gemm_bf16_k<64, true, false, true, false, false, true, false><<<dim3(4, 64), 256, 0, stream>>>(
                ff116, wff216 + (size_t)l * 512 * 2048, enc_ff2_b + l * 512, x, x, nullptr, 4096, 512, 2048);
    }

    // 3) cross-attention
    gather_k<<<2048, 128, 0, stream>>>(gene_embed, gene_ids, ge16);
    gemm_bf16_k<64, true, false, false, false, false, false, true><<<dim3(4, 32), 256, 0, stream>>>(
        ge16, wcaqkv16, ca_qkv_b, nullptr, nullptr, qg16, 2048, 512, 512);
    gemm_bf16_k<64, true, false, false, false, false, false, true><<<dim3(4, 64), 256, 0, stream>>>(
        x16, wcaqkv16 + (size_t)512 * 512, ca_qkv_b + 512, nullptr, nullptr, kc16, 4096, 512, 512);
    gemm_bf16_k<64, true, true, false, false, false, false, true><<<dim3(32, 8), 256, 0, stream>>>(
        wcaqkv16 + (size_t)1024 * 512, x16, ca_qkv_b + 1024, nullptr, nullptr, vt16, 512, 4096, 512);
    flashb_k<<<dim3(32, 8, 8), 256, 0, stream>>>(
        qg16, 0LL, 512,
        kc16, (long long)512 * 512, 512,
        vt16, (long long)64 * 4096, 512LL, 4096,
        oc16, (long long)2048 * 512, 512, 512);
    gemm_bf16_k<128, true, false, false, false, false, true, false><<<dim3(4, 128), 256, 0, stream>>>(
        oc16, wcaout16, ca_out_b, nullptr, z, nullptr, 16384, 512, 512);

    // 4) readout
    readout_k<<<16384, 64, 0, stream>>>(z, ro_ln_g, ro_ln_b, ro_w, ro_b, pred);
}